// Round 1
// baseline (936.130 us; speedup 1.0000x reference)
//
#include <hip/hip_runtime.h>
#include <hip/hip_bf16.h>

typedef __hip_bfloat16 bf16;
typedef _Float16 h16;
typedef __attribute__((ext_vector_type(8))) _Float16 half8;
typedef __attribute__((ext_vector_type(4))) float f32x4;

#define NQ 128
#define HD 512
#define FD 256
#define NC 6
#define IMH 48
#define IMW 120
#define HW 5760   // 48*120

__device__ __forceinline__ half8 pack8(float4 x, float4 y) {
    half8 h;
    h[0] = (h16)x.x; h[1] = (h16)x.y; h[2] = (h16)x.z; h[3] = (h16)x.w;
    h[4] = (h16)y.x; h[5] = (h16)y.y; h[6] = (h16)y.z; h[7] = (h16)y.w;
    return h;
}

// ---------------------------------------------------------------------------
// Transpose features (NC, FD, HW) f32  ->  (NC, HW, FD) bf16
// ---------------------------------------------------------------------------
__global__ __launch_bounds__(256) void transpose_feat_k(const float* __restrict__ f,
                                                        bf16* __restrict__ ft)
{
    __shared__ float tile[32][33];
    int cam = blockIdx.z;
    int hw0 = blockIdx.x * 32, fd0 = blockIdx.y * 32;
    int tx = threadIdx.x, ty = threadIdx.y;
    const float* fb = f + (size_t)cam * FD * HW;
    for (int r = ty; r < 32; r += 8)
        tile[r][tx] = fb[(size_t)(fd0 + r) * HW + hw0 + tx];
    __syncthreads();
    bf16* fo = ft + (size_t)cam * HW * FD;
    for (int r = ty; r < 32; r += 8)
        fo[(size_t)(hw0 + r) * FD + fd0 + tx] = __float2bfloat16(tile[tx][r]);
}

// fp32 -> fp16 copy (queries0)
__global__ __launch_bounds__(256) void cvt16_k(const float* __restrict__ src,
                                               h16* __restrict__ dst, int n)
{
    int i = blockIdx.x * 256 + threadIdx.x;
    if (i < n) dst[i] = (h16)src[i];
}

// ---------------------------------------------------------------------------
// Split-K-in-block MFMA GEMM reading fp32 row-major weights DIRECTLY
// (B fragment packed to fp16 in registers -- no pre-swizzle pass).
// 256 thr = 4 waves; wave w computes K-quarter w of the same (m0, n-group)
// tile(s); LDS-combined (no atomics). grid (N/(16*CTN), M/16).
// A: fp16 row-major (NSUM slabs summed) or fp32 + fused LayerNorm (LNA).
// A2SW: blocks bx>=a2Start read A2 (fp16, no LN) -- merged cross-attn q/kv.
// LNA && bx==0: wave w also writes its normalized K-quarter to lnout.
// W tri-section (W1f != nullptr): rows [0,512) from W0f, [512,1024) W1f,
// [1024,1536) W2f -- mirrors the bias tri-section (concatenated heads).
// ---------------------------------------------------------------------------
template<int CTN, int NSUM, bool A2SW, bool LNA>
__global__ __launch_bounds__(256) void gemm_sk4(
    const h16* __restrict__ A16, int lda, int sumStride,
    const float* __restrict__ A32,
    const float* __restrict__ lng, const float* __restrict__ lnb,
    float* __restrict__ lnout,
    const h16* __restrict__ A2_16, int a2Start,
    const float* __restrict__ W0f, const float* __restrict__ W1f, const float* __restrict__ W2f,
    const float* __restrict__ B0, const float* __restrict__ B1, const float* __restrict__ B2s,
    const float* __restrict__ R, int ldr,
    float* __restrict__ C32, h16* __restrict__ C16, int ldc,
    int K, int act)
{
    __shared__ float redu[CTN * 4 * 256];
    __shared__ float sst[64], sst2[64];
    int bx = blockIdx.x, by = blockIdx.y;
    int tid = threadIdx.x;
    int w = tid >> 6, l = tid & 63;
    int lr = l & 15, q4 = l >> 4;
    int m0 = by * 16;
    int n0 = bx * 16 * CTN;
    int row = m0 + lr;
    int K32 = K >> 5;
    int KQ = K32 >> 2;
    int ks0 = w * KQ;

    bool useA2 = A2SW && (bx >= a2Start);

    const float* arow32 = nullptr;
    float mean = 0.f, rstd = 1.f;
    if (LNA && !useA2) {
        arow32 = A32 + (size_t)row * K + q4 * 8;
        float s = 0.f, s2 = 0.f;
        for (int ks = ks0; ks < ks0 + KQ; ks++) {
            float4 u = *(const float4*)(arow32 + ks * 32);
            float4 v = *(const float4*)(arow32 + ks * 32 + 4);
            s  += u.x + u.y + u.z + u.w + v.x + v.y + v.z + v.w;
            s2 += u.x*u.x + u.y*u.y + u.z*u.z + u.w*u.w
                + v.x*v.x + v.y*v.y + v.z*v.z + v.w*v.w;
        }
        s  += __shfl_xor(s, 16);  s  += __shfl_xor(s, 32);
        s2 += __shfl_xor(s2, 16); s2 += __shfl_xor(s2, 32);
        if (q4 == 0) { sst[w * 16 + lr] = s; sst2[w * 16 + lr] = s2; }
        __syncthreads();
        float st = sst[lr] + sst[16 + lr] + sst[32 + lr] + sst[48 + lr];
        float st2 = sst2[lr] + sst2[16 + lr] + sst2[32 + lr] + sst2[48 + lr];
        mean = st * (1.0f / (float)K);
        float var = st2 * (1.0f / (float)K) - mean * mean;
        rstd = rsqrtf(var + 1e-5f);
    }

    const h16* arow16 = nullptr;
    if (useA2)       arow16 = A2_16 + (size_t)row * 512 + q4 * 8;
    else if (!LNA)   arow16 = A16 + (size_t)row * lda + q4 * 8;

    // per-tile fp32 weight row pointer: lane l covers W[n0+ct*16+lr][ks*32+q4*8 ..+8]
    const float* wrow[CTN];
#pragma unroll
    for (int ct = 0; ct < CTN; ct++) {
        int nb = n0 + ct * 16;
        const float* ws;
        if (W1f) {
            int sec = nb >> 9, ni = nb & 511;
            ws = (sec == 0 ? W0f : (sec == 1 ? W1f : W2f)) + (size_t)ni * K;
        } else {
            ws = W0f + (size_t)nb * K;
        }
        wrow[ct] = ws + (size_t)lr * K + q4 * 8;
    }

    f32x4 acc[CTN];
#pragma unroll
    for (int ct = 0; ct < CTN; ct++) acc[ct] = (f32x4){0.f, 0.f, 0.f, 0.f};

    bool wrln = LNA && !useA2 && (bx == 0) && lnout;

#pragma unroll 4
    for (int ks = ks0; ks < ks0 + KQ; ks++) {
        half8 a;
        if (LNA && !useA2) {
            float4 u = *(const float4*)(arow32 + ks * 32);
            float4 v = *(const float4*)(arow32 + ks * 32 + 4);
            float4 g0 = *(const float4*)(lng + ks * 32 + q4 * 8);
            float4 g1 = *(const float4*)(lng + ks * 32 + q4 * 8 + 4);
            float4 b0 = *(const float4*)(lnb + ks * 32 + q4 * 8);
            float4 b1 = *(const float4*)(lnb + ks * 32 + q4 * 8 + 4);
            float4 o0, o1;
            o0.x = (u.x - mean) * rstd * g0.x + b0.x;
            o0.y = (u.y - mean) * rstd * g0.y + b0.y;
            o0.z = (u.z - mean) * rstd * g0.z + b0.z;
            o0.w = (u.w - mean) * rstd * g0.w + b0.w;
            o1.x = (v.x - mean) * rstd * g1.x + b1.x;
            o1.y = (v.y - mean) * rstd * g1.y + b1.y;
            o1.z = (v.z - mean) * rstd * g1.z + b1.z;
            o1.w = (v.w - mean) * rstd * g1.w + b1.w;
            if (wrln) {
                *(float4*)(lnout + (size_t)row * K + ks * 32 + q4 * 8)     = o0;
                *(float4*)(lnout + (size_t)row * K + ks * 32 + q4 * 8 + 4) = o1;
            }
            a = pack8(o0, o1);
        } else if (NSUM == 1) {
            a = *(const half8*)(arow16 + (size_t)ks * 32);
        } else {
            float s[8] = {0.f, 0.f, 0.f, 0.f, 0.f, 0.f, 0.f, 0.f};
#pragma unroll
            for (int j = 0; j < NSUM; j++) {
                half8 tt = *(const half8*)(arow16 + (size_t)j * sumStride + ks * 32);
#pragma unroll
                for (int e = 0; e < 8; e++) s[e] += (float)tt[e];
            }
#pragma unroll
            for (int e = 0; e < 8; e++) a[e] = (h16)s[e];
        }
#pragma unroll
        for (int ct = 0; ct < CTN; ct++) {
            const float* wp = wrow[ct] + (size_t)ks * 32;
            float4 wu = *(const float4*)(wp);
            float4 wv = *(const float4*)(wp + 4);
            half8 bfr = pack8(wu, wv);
            acc[ct] = __builtin_amdgcn_mfma_f32_16x16x32_f16(a, bfr, acc[ct], 0, 0, 0);
        }
    }

#pragma unroll
    for (int ct = 0; ct < CTN; ct++)
        *(f32x4*)&redu[(size_t)(w * CTN + ct) * 256 + l * 4] = acc[ct];
    __syncthreads();

    if (w < CTN) {
        int ct = w;
        f32x4 sum = *(const f32x4*)&redu[(size_t)ct * 256 + l * 4];
#pragma unroll
        for (int w2 = 1; w2 < 4; w2++) {
            f32x4 tt = *(const f32x4*)&redu[(size_t)(w2 * CTN + ct) * 256 + l * 4];
            sum[0] += tt[0]; sum[1] += tt[1]; sum[2] += tt[2]; sum[3] += tt[3];
        }
        int n = n0 + ct * 16 + lr;
        float bv;
        if (B1) { int sec = n >> 9, ni = n & 511;
                  bv = (sec == 0) ? B0[ni] : (sec == 1 ? B1[ni] : B2s[ni]); }
        else bv = B0[n];
#pragma unroll
        for (int r = 0; r < 4; r++) {
            int m = m0 + q4 * 4 + r;
            float v = sum[r] + bv;
            if (act) v = fmaxf(v, 0.f);
            if (R) v += R[(size_t)m * ldr + n];
            if (C32) C32[(size_t)m * ldc + n] = v;
            if (C16) C16[(size_t)m * ldc + n] = (h16)v;
        }
    }
}

// ---------------------------------------------------------------------------
// Head output: out[q][n] = act( hid16_row . w2_row + b ), into d_out.
// ---------------------------------------------------------------------------
__global__ __launch_bounds__(64) void heads2_k(const h16* __restrict__ hid16,
                                               const float* __restrict__ w2m, const float* __restrict__ b2m,
                                               const float* __restrict__ w2t, const float* __restrict__ b2t,
                                               const float* __restrict__ w2a, const float* __restrict__ b2a,
                                               const float* __restrict__ pmin, const float* __restrict__ pmax,
                                               float* __restrict__ out)
{
    int q = blockIdx.x, n = blockIdx.y, lane = threadIdx.x;
    const float* wr; float bv; int mode, sect;
    if (n < 11)      { sect = 0; wr = w2m + n * 512;        bv = b2m[n];      mode = 0; }
    else if (n < 21) { sect = 1; wr = w2t + (n - 11) * 512; bv = b2t[n - 11]; mode = 1; }
    else             { sect = 2; wr = w2a + (n - 21) * 512; bv = b2a[n - 21]; mode = 2; }
    half8 hv = *(const half8*)(hid16 + q * 1536 + sect * 512 + lane * 8);
    const float4* w4 = (const float4*)(wr + lane * 8);
    float4 c0 = w4[0], c1 = w4[1];
    float acc = (float)hv[0] * c0.x + (float)hv[1] * c0.y
              + (float)hv[2] * c0.z + (float)hv[3] * c0.w
              + (float)hv[4] * c1.x + (float)hv[5] * c1.y
              + (float)hv[6] * c1.z + (float)hv[7] * c1.w;
    for (int off = 32; off; off >>= 1) acc += __shfl_xor(acc, off);
    if (lane == 0) {
        float v = acc + bv;
        if (mode == 0)      v = (1.0f / (1.0f + __expf(-v))) * (pmax[n] - pmin[n]) + pmin[n];
        else if (mode == 2) v = 1.0f / (1.0f + __expf(-v));
        out[q * 24 + n] = v;
    }
}

// ---------------------------------------------------------------------------
// MHA core on packed qkv (128 x 1536 = [Q|K|V] fp32), fp16 output.
// ---------------------------------------------------------------------------
__global__ __launch_bounds__(256) void attn_k(const float* __restrict__ qkv,
                                              h16* __restrict__ out16)
{
    __shared__ float KVl[128 * 68];
    __shared__ float Ql[32 * 68];
    __shared__ float Pl[32 * 128];
    int h = blockIdx.x >> 2, chunk = blockIdx.x & 3;
    int tid = threadIdx.x;

    for (int l = tid; l < 2048; l += 256) {
        int row = l >> 4, c4 = (l & 15) * 4;
        float4 v = *(const float4*)&qkv[row * 1536 + 512 + h * 64 + c4];
        *(float4*)&KVl[row * 68 + c4] = v;
    }
    for (int l = tid; l < 512; l += 256) {
        int row = l >> 4, c4 = (l & 15) * 4;
        float4 v = *(const float4*)&qkv[(chunk * 32 + row) * 1536 + h * 64 + c4];
        *(float4*)&Ql[row * 68 + c4] = v;
    }
    __syncthreads();

    int w = tid >> 6, j = tid & 63;
    for (int r8 = 0; r8 < 8; r8++) {
        int lr = w * 8 + r8;
        float s0 = 0.f, s1 = 0.f;
#pragma unroll
        for (int k4 = 0; k4 < 64; k4 += 4) {
            float4 qv  = *(const float4*)&Ql[lr * 68 + k4];
            float4 k0v = *(const float4*)&KVl[j * 68 + k4];
            float4 k1v = *(const float4*)&KVl[(j + 64) * 68 + k4];
            s0 += qv.x * k0v.x + qv.y * k0v.y + qv.z * k0v.z + qv.w * k0v.w;
            s1 += qv.x * k1v.x + qv.y * k1v.y + qv.z * k1v.z + qv.w * k1v.w;
        }
        s0 *= 0.125f; s1 *= 0.125f;
        float m = fmaxf(s0, s1);
        for (int off = 32; off; off >>= 1) m = fmaxf(m, __shfl_xor(m, off));
        float e0 = __expf(s0 - m), e1 = __expf(s1 - m);
        float sm = e0 + e1;
        for (int off = 32; off; off >>= 1) sm += __shfl_xor(sm, off);
        float inv = 1.0f / sm;
        Pl[lr * 128 + j]      = e0 * inv;
        Pl[lr * 128 + j + 64] = e1 * inv;
    }
    __syncthreads();

    for (int l = tid; l < 2048; l += 256) {
        int row = l >> 4, c4 = (l & 15) * 4;
        float4 v = *(const float4*)&qkv[row * 1536 + 1024 + h * 64 + c4];
        KVl[(c4 + 0) * 132 + row] = v.x;
        KVl[(c4 + 1) * 132 + row] = v.y;
        KVl[(c4 + 2) * 132 + row] = v.z;
        KVl[(c4 + 3) * 132 + row] = v.w;
    }
    __syncthreads();

    int d = tid & 63, w2 = tid >> 6;
    for (int r8 = 0; r8 < 8; r8++) {
        int lr = w2 * 8 + r8;
        float o = 0.f;
#pragma unroll
        for (int j4 = 0; j4 < 128; j4 += 4) {
            float4 pv = *(const float4*)&Pl[lr * 128 + j4];
            float4 vv = *(const float4*)&KVl[d * 132 + j4];
            o += pv.x * vv.x + pv.y * vv.y + pv.z * vv.z + pv.w * vv.w;
        }
        out16[(chunk * 32 + lr) * 512 + h * 64 + d] = (h16)o;
    }
}

// ---------------------------------------------------------------------------
// Gather: grid (128 queries, 6 cams). Compacted taps; fp16 slab out.
// ---------------------------------------------------------------------------
__device__ __forceinline__ float bflo(unsigned u) {
    union { unsigned i; float f; } c; c.i = u << 16; return c.f;
}
__device__ __forceinline__ float bfhi(unsigned u) {
    union { unsigned i; float f; } c; c.i = u & 0xffff0000u; return c.f;
}

__global__ __launch_bounds__(256) void gather_k(const bf16* __restrict__ ft,
                                                const float* __restrict__ proj,
                                                const float* __restrict__ preds,
                                                h16* __restrict__ agg16)
{
    __shared__ float mo[11];
    __shared__ int   goff[384];
    __shared__ float gw[384];
    __shared__ int   cnt;
    __shared__ float part[8][256];
    int n = blockIdx.x, cam = blockIdx.y, tid = threadIdx.x;
    if (tid == 0) cnt = 0;
    if (tid < 11) mo[tid] = preds[n * 24 + tid];
    __syncthreads();

    if (tid < 96) {
        int p = tid;
        float dd0 = mo[8], dd1 = mo[9], dd2 = mo[10];
        float c0 = mo[0], c1 = mo[1], c2 = mo[2];
        float sy, cy;
        sincosf(mo[7], &sy, &cy);
        int face = p >> 4, axis = face >> 1;
        float sgn = (face & 1) ? 0.5f : -0.5f;
        float offi = -0.4f + (float)((p >> 2) & 3) * (0.8f / 3.0f);
        float offj = -0.4f + (float)(p & 3) * (0.8f / 3.0f);
        float t0, t1, t2;
        if (axis == 0)      { t0 = sgn;  t1 = offi; t2 = offj; }
        else if (axis == 1) { t0 = offi; t1 = sgn;  t2 = offj; }
        else                { t0 = offi; t1 = offj; t2 = sgn;  }
        float px = t0 * dd0, py = t1 * dd1, pz = t2 * dd2;
        float X = px * cy - py * sy + c0;
        float Y = px * sy + py * cy + c1;
        float Z = pz + c2;
        const float* P = proj + cam * 12;
        float cu = P[0] * X + P[1] * Y + P[2] * Z + P[3];
        float cv = P[4] * X + P[5] * Y + P[6] * Z + P[7];
        float cz = P[8] * X + P[9] * Y + P[10] * Z + P[11];
        float zs = (fabsf(cz) > 1e-6f) ? cz : 1e-6f;
        float u = cu / zs, v = cv / zs;
        bool front = cz > 0.0f;
        float u0 = floorf(u), v0 = floorf(v);
        float du = u - u0, dv = v - v0;
        float us[4] = {u0, u0 + 1.0f, u0, u0 + 1.0f};
        float vs[4] = {v0, v0, v0 + 1.0f, v0 + 1.0f};
        float wt[4] = {(1.0f - du) * (1.0f - dv), du * (1.0f - dv),
                       (1.0f - du) * dv, du * dv};
        int   myoff[4]; float myw[4]; int k = 0;
#pragma unroll
        for (int t = 0; t < 4; t++) {
            bool ok = front && (us[t] >= 0.0f) && (us[t] <= 119.0f)
                            && (vs[t] >= 0.0f) && (vs[t] <= 47.0f)
                            && (wt[t] > 0.0f);
            if (ok) {
                myoff[k] = ((int)vs[t] * IMW + (int)us[t]) * FD;
                myw[k]   = wt[t];
                k++;
            }
        }
        if (k) {
            int base = atomicAdd(&cnt, k);
            for (int s = 0; s < k; s++) { goff[base + s] = myoff[s]; gw[base + s] = myw[s]; }
        }
    }
    __syncthreads();
    int C = cnt;
    h16* slab = agg16 + (size_t)cam * 32768 + n * 256;
    if (C == 0) { slab[tid] = (h16)0.f; return; }

    int g8  = (tid & 31) * 8;
    int row = tid >> 5;
    const bf16* fb = ft + (size_t)cam * HW * FD + g8;
    float acc[8] = {0.f, 0.f, 0.f, 0.f, 0.f, 0.f, 0.f, 0.f};
    for (int e = row; e < C; e += 8) {
        float w = gw[e];
        uint4 rv = *(const uint4*)(fb + goff[e]);
        acc[0] += w * bflo(rv.x); acc[1] += w * bfhi(rv.x);
        acc[2] += w * bflo(rv.y); acc[3] += w * bfhi(rv.y);
        acc[4] += w * bflo(rv.z); acc[5] += w * bfhi(rv.z);
        acc[6] += w * bflo(rv.w); acc[7] += w * bfhi(rv.w);
    }
#pragma unroll
    for (int j = 0; j < 8; j++) part[row][g8 + j] = acc[j];
    __syncthreads();
    float s = 0.f;
#pragma unroll
    for (int r = 0; r < 8; r++) s += part[r][tid];
    slab[tid] = (h16)(s * (1.0f / 576.0f));
}

// ---------------------------------------------------------------------------
extern "C" void kernel_launch(void* const* d_in, const int* in_sizes, int n_in,
                              void* d_out, int out_size, void* d_ws, size_t ws_size,
                              hipStream_t stream)
{
    const float* features  = (const float*)d_in[0];
    const float* proj      = (const float*)d_in[1];
    const float* queries0  = (const float*)d_in[3];
    const float* pmin      = (const float*)d_in[4];
    const float* pmax      = (const float*)d_in[5];
    const float* motion_w1 = (const float*)d_in[6];
    const float* motion_b1 = (const float*)d_in[7];
    const float* motion_w2 = (const float*)d_in[8];
    const float* motion_b2 = (const float*)d_in[9];
    const float* type_w1   = (const float*)d_in[10];
    const float* type_b1   = (const float*)d_in[11];
    const float* type_w2   = (const float*)d_in[12];
    const float* type_b2   = (const float*)d_in[13];
    const float* attr_w1   = (const float*)d_in[14];
    const float* attr_b1   = (const float*)d_in[15];
    const float* attr_w2   = (const float*)d_in[16];
    const float* attr_b2   = (const float*)d_in[17];
    const float* fmlp_w1   = (const float*)d_in[18];
    const float* fmlp_b1   = (const float*)d_in[19];
    const float* fmlp_w2   = (const float*)d_in[20];
    const float* fmlp_b2   = (const float*)d_in[21];
    const float* sa_in_w   = (const float*)d_in[22];
    const float* sa_in_b   = (const float*)d_in[23];
    const float* sa_out_w  = (const float*)d_in[24];
    const float* sa_out_b  = (const float*)d_in[25];
    const float* fa_in_w   = (const float*)d_in[26];
    const float* fa_in_b   = (const float*)d_in[27];
    const float* fa_out_w  = (const float*)d_in[28];
    const float* fa_out_b  = (const float*)d_in[29];
    const float* ffn_w1    = (const float*)d_in[30];
    const float* ffn_b1    = (const float*)d_in[31];
    const float* ffn_w2    = (const float*)d_in[32];
    const float* ffn_b2    = (const float*)d_in[33];
    const float* ln1_g     = (const float*)d_in[34];
    const float* ln1_b     = (const float*)d_in[35];
    const float* ln2_g     = (const float*)d_in[36];
    const float* ln2_b     = (const float*)d_in[37];
    const float* ln3_g     = (const float*)d_in[38];
    const float* ln3_b     = (const float*)d_in[39];
    float* out = (float*)d_out;

    // ---- workspace ----
    char* p = (char*)d_ws;
    bf16* feat_t = (bf16*)p;   p += (size_t)NC * HW * FD * 2;        // 17.7 MB
    h16* q016    = (h16*)p;    p += 65536 * 2;
    h16* hid16   = (h16*)p;    p += 196608 * 2;
    h16* agg16   = (h16*)p;    p += 196608 * 2;
    h16* fmlph16 = (h16*)p;    p += 65536 * 2;
    h16* feath16 = (h16*)p;    p += 65536 * 2;
    h16* attnb16 = (h16*)p;    p += 65536 * 2;
    h16* ffnh16  = (h16*)p;    p += 262144 * 2;
    h16* qn16    = (h16*)p;    p += 65536 * 2;
    float* qkv   = (float*)p;  p += 196608 * 4;
    float* lnx   = (float*)p;  p += 65536 * 4;
    float* x1    = (float*)p;  p += 65536 * 4;
    float* x2    = (float*)p;  p += 65536 * 4;
    float* qn32  = (float*)p;  p += 65536 * 4;

    // ---- one-time prep ----
    cvt16_k<<<256, 256, 0, stream>>>(queries0, q016, 65536);
    transpose_feat_k<<<dim3(180, 8, 6), dim3(32, 8), 0, stream>>>(features, feat_t);

    const h16*   q16 = q016;
    const float* q32 = queries0;

    for (int i = 0; i < 6; i++) {
        // prediction heads (tri-section fp32 W: motion|type|attr, N=1536, K=512)
        gemm_sk4<2, 1, false, false><<<dim3(48, 8), 256, 0, stream>>>(
            q16, 512, 0, nullptr, nullptr, nullptr, nullptr, nullptr, 0,
            motion_w1, type_w1, attr_w1,
            motion_b1, type_b1, attr_b1, nullptr, 0,
            nullptr, hid16, 1536, 512, 1);
        heads2_k<<<dim3(128, 24), 64, 0, stream>>>(hid16, motion_w2, motion_b2,
                                                   type_w2, type_b2, attr_w2, attr_b2,
                                                   pmin, pmax, out + i * 3072);
        if (i == 5) break;

        // feature gather + feature MLP
        gather_k<<<dim3(128, 6), 256, 0, stream>>>(feat_t, proj, out + i * 3072, agg16);
        gemm_sk4<1, 6, false, false><<<dim3(32, 8), 256, 0, stream>>>(
            agg16, 256, 32768, nullptr, nullptr, nullptr, nullptr, nullptr, 0,
            fmlp_w1, nullptr, nullptr,
            fmlp_b1, nullptr, nullptr, nullptr, 0,
            nullptr, fmlph16, 512, 256, 1);
        gemm_sk4<1, 1, false, false><<<dim3(32, 8), 256, 0, stream>>>(
            fmlph16, 512, 0, nullptr, nullptr, nullptr, nullptr, nullptr, 0,
            fmlp_w2, nullptr, nullptr,
            fmlp_b2, nullptr, nullptr, nullptr, 0,
            nullptr, feath16, 512, 512, 0);

        // self-attention (LN1 fused into qkv projection)
        gemm_sk4<2, 1, false, true><<<dim3(48, 8), 256, 0, stream>>>(
            nullptr, 0, 0, q32, ln1_g + i * 512, ln1_b + i * 512, lnx, nullptr, 0,
            sa_in_w + (size_t)i * 1536 * 512, nullptr, nullptr,
            sa_in_b + i * 1536, nullptr, nullptr,
            nullptr, 0, qkv, nullptr, 1536, 512, 0);
        attn_k<<<32, 256, 0, stream>>>(qkv, attnb16);
        gemm_sk4<1, 1, false, false><<<dim3(32, 8), 256, 0, stream>>>(
            attnb16, 512, 0, nullptr, nullptr, nullptr, nullptr, nullptr, 0,
            sa_out_w + (size_t)i * 512 * 512, nullptr, nullptr,
            sa_out_b + i * 512, nullptr, nullptr,
            lnx, 512, x1, nullptr, 512, 512, 0);

        // cross-attention (LN2 fused; kv side reads feath16 via A2 switch)
        gemm_sk4<2, 1, true, true><<<dim3(48, 8), 256, 0, stream>>>(
            nullptr, 0, 0, x1, ln2_g + i * 512, ln2_b + i * 512, lnx, feath16, 16,
            fa_in_w + (size_t)i * 1536 * 512, nullptr, nullptr,
            fa_in_b + i * 1536, nullptr, nullptr,
            nullptr, 0, qkv, nullptr, 1536, 512, 0);
        attn_k<<<32, 256, 0, stream>>>(qkv, attnb16);
        gemm_sk4<1, 1, false, false><<<dim3(32, 8), 256, 0, stream>>>(
            attnb16, 512, 0, nullptr, nullptr, nullptr, nullptr, nullptr, 0,
            fa_out_w + (size_t)i * 512 * 512, nullptr, nullptr,
            fa_out_b + i * 512, nullptr, nullptr,
            lnx, 512, x2, nullptr, 512, 512, 0);

        // FFN (LN3 fused into ffn1)
        gemm_sk4<2, 1, false, true><<<dim3(64, 8), 256, 0, stream>>>(
            nullptr, 0, 0, x2, ln3_g + i * 512, ln3_b + i * 512, lnx, nullptr, 0,
            ffn_w1 + (size_t)i * 2048 * 512, nullptr, nullptr,
            ffn_b1 + i * 2048, nullptr, nullptr,
            nullptr, 0, nullptr, ffnh16, 2048, 512, 1);
        gemm_sk4<1, 1, false, false><<<dim3(32, 8), 256, 0, stream>>>(
            ffnh16, 2048, 0, nullptr, nullptr, nullptr, nullptr, nullptr, 0,
            ffn_w2 + (size_t)i * 512 * 2048, nullptr, nullptr,
            ffn_b2 + i * 512, nullptr, nullptr,
            lnx, 512, qn32, qn16, 512, 2048, 0);

        q16 = qn16;
        q32 = qn32;
    }
}

// Round 2
// 863.479 us; speedup vs baseline: 1.0841x; 1.0841x over previous
//
#include <hip/hip_runtime.h>
#include <hip/hip_bf16.h>

typedef __hip_bfloat16 bf16;
typedef _Float16 h16;
typedef __attribute__((ext_vector_type(8))) _Float16 half8;
typedef __attribute__((ext_vector_type(4))) _Float16 half4;
typedef __attribute__((ext_vector_type(4))) float f32x4;

#define NQ 128
#define HD 512
#define FD 256
#define NC 6
#define IMH 48
#define IMW 120
#define HW 5760   // 48*120

__device__ __forceinline__ half8 pack8(float4 x, float4 y) {
    half8 h;
    h[0] = (h16)x.x; h[1] = (h16)x.y; h[2] = (h16)x.z; h[3] = (h16)x.w;
    h[4] = (h16)y.x; h[5] = (h16)y.y; h[6] = (h16)y.z; h[7] = (h16)y.w;
    return h;
}

// ---------------------------------------------------------------------------
// Transpose features (NC, FD, HW) f32  ->  (NC, HW, FD) bf16
// ---------------------------------------------------------------------------
__global__ __launch_bounds__(256) void transpose_feat_k(const float* __restrict__ f,
                                                        bf16* __restrict__ ft)
{
    __shared__ float tile[32][33];
    int cam = blockIdx.z;
    int hw0 = blockIdx.x * 32, fd0 = blockIdx.y * 32;
    int tx = threadIdx.x, ty = threadIdx.y;
    const float* fb = f + (size_t)cam * FD * HW;
    for (int r = ty; r < 32; r += 8)
        tile[r][tx] = fb[(size_t)(fd0 + r) * HW + hw0 + tx];
    __syncthreads();
    bf16* fo = ft + (size_t)cam * HW * FD;
    for (int r = ty; r < 32; r += 8)
        fo[(size_t)(hw0 + r) * FD + fd0 + tx] = __float2bfloat16(tile[tx][r]);
}

// fp32 -> fp16 copy (queries0)
__global__ __launch_bounds__(256) void cvt16_k(const float* __restrict__ src,
                                               h16* __restrict__ dst, int n)
{
    int i = blockIdx.x * 256 + threadIdx.x;
    if (i < n) dst[i] = (h16)src[i];
}

// ---------------------------------------------------------------------------
// Weight swizzle v3: fp32 row-major -> fp16 MFMA B-fragment tiles.
// Same dst layout & block->chunk decode as v2 (each block: 64 rows x 64 cols,
// 8 output tiles of 512 halfs), but:
//  - global reads in 256B dense segments (16 consecutive lanes per row)
//  - each float4 packed to ONE aligned 8B LDS store (was 4x scalar 2B)
//  - LDS lane slot XOR-permuted (same bijection on store & read) to spread
//    the fragment-layout stores across all 32 banks.
// Tile (global n-tile tct, ks): lane l holds W[(tct>>2)*64+(tct&3)*16+(l&15)]
// [ks*32 + (l>>4)*8 + j], stored 64 lanes x 16B contiguous (1KB).
// dst tile offset = (tileStart[w] + (n64*K32 + ks)*4 + ct) * 512 halfs.
// ---------------------------------------------------------------------------
struct SwzDesc {
    const float* src[11];
    unsigned int chunkStart[12];   // block-id boundaries
    unsigned int tileStart[11];    // dst tile base
    int K[11];
};

__device__ __forceinline__ int lperm(int lane, int ksl) {
    return lane ^ ((lane >> 4) & 3) ^ (ksl << 2);
}

__global__ __launch_bounds__(256) void swizzle3_k(SwzDesc d, h16* __restrict__ dst)
{
    __shared__ h16 fbuf[4096];     // 8 tiles x 512 halfs = 8KB
    int bid = blockIdx.x;
    int w = 0;
    while (bid >= (int)d.chunkStart[w + 1]) w++;
    int local = bid - (int)d.chunkStart[w];
    int Kk = d.K[w];
    int kc = Kk >> 6;              // 64-col chunks per row group
    int n64 = local / kc, kchunk = local - n64 * kc;
    int t = threadIdx.x;

    // read mapping: pass rp covers rows rp*16 + rr; lane reads float4 at col cb
    int rr  = t >> 4;              // 0..15 row within pass-group
    int cb  = (t & 15) * 4;        // 0..60, 16 lanes contiguous = 256B segment
    int ksl = (t >> 3) & 1;        // cb>>5
    int kk  = cb & 31;
    int laneb = ((kk >> 3) << 4) + rr;   // fragment lane = (kk>>3)*16 + row&15
    int elemB = (kk & 7) * 2;            // byte offset within lane's 16B: 0 or 8
    const float* sbase = d.src[w] + (size_t)(n64 * 64 + rr) * Kk + kchunk * 64 + cb;
#pragma unroll
    for (int rp = 0; rp < 4; rp++) {
        float4 u = *(const float4*)(sbase + (size_t)rp * 16 * Kk);
        int tile8 = ksl * 4 + rp;        // ct == rp for this pass
        int l2 = lperm(laneb, ksl);
        half4* fp = (half4*)((char*)fbuf + tile8 * 1024 + l2 * 16 + elemB);
        half4 hv; hv[0] = (h16)u.x; hv[1] = (h16)u.y; hv[2] = (h16)u.z; hv[3] = (h16)u.w;
        *fp = hv;
    }
    __syncthreads();

    int K32 = Kk >> 5;
#pragma unroll
    for (int i = 0; i < 2; i++) {
        int hidx = t + i * 256;            // 16B chunk id, 0..511
        int tl = hidx >> 6, within = hidx & 63;
        int ksl2 = tl >> 2, ctt = tl & 3;
        int l2 = lperm(within, ksl2);
        size_t tileg = (size_t)d.tileStart[w]
                     + ((size_t)n64 * K32 + (kchunk * 2 + ksl2)) * 4 + ctt;
        *(half8*)(dst + tileg * 512 + within * 8) =
            *(const half8*)((const char*)fbuf + tl * 1024 + l2 * 16);
    }
}

// ---------------------------------------------------------------------------
// Split-K-in-block MFMA GEMM on swizzled fp16 weights. 256 thr = 4 waves;
// wave w computes K-quarter w of the same (m0, n-group) tile(s); LDS-combined
// (no atomics). grid (N/(16*CTN), M/16).
// A: fp16 row-major (NSUM slabs summed) or fp32 + fused LayerNorm (LNA).
// A2SW: blocks bx>=a2Start read A2 (fp16, no LN) -- merged cross-attn q/kv.
// LNA && bx==0: wave w also writes its normalized K-quarter to lnout.
// ---------------------------------------------------------------------------
template<int CTN, int NSUM, bool A2SW, bool LNA>
__global__ __launch_bounds__(256) void gemm_sk4(
    const h16* __restrict__ A16, int lda, int sumStride,
    const float* __restrict__ A32,
    const float* __restrict__ lng, const float* __restrict__ lnb,
    float* __restrict__ lnout,
    const h16* __restrict__ A2_16, int a2Start,
    const h16* __restrict__ Wswz,
    const float* __restrict__ B0, const float* __restrict__ B1, const float* __restrict__ B2s,
    const float* __restrict__ R, int ldr,
    float* __restrict__ C32, h16* __restrict__ C16, int ldc,
    int K, int act)
{
    __shared__ float redu[CTN * 4 * 256];
    __shared__ float sst[64], sst2[64];
    int bx = blockIdx.x, by = blockIdx.y;
    int tid = threadIdx.x;
    int w = tid >> 6, l = tid & 63;
    int lr = l & 15, q4 = l >> 4;
    int m0 = by * 16;
    int n0 = bx * 16 * CTN;
    int row = m0 + lr;
    int K32 = K >> 5;
    int KQ = K32 >> 2;
    int ks0 = w * KQ;

    bool useA2 = A2SW && (bx >= a2Start);

    const float* arow32 = nullptr;
    float mean = 0.f, rstd = 1.f;
    if (LNA && !useA2) {
        arow32 = A32 + (size_t)row * K + q4 * 8;
        float s = 0.f, s2 = 0.f;
        for (int ks = ks0; ks < ks0 + KQ; ks++) {
            float4 u = *(const float4*)(arow32 + ks * 32);
            float4 v = *(const float4*)(arow32 + ks * 32 + 4);
            s  += u.x + u.y + u.z + u.w + v.x + v.y + v.z + v.w;
            s2 += u.x*u.x + u.y*u.y + u.z*u.z + u.w*u.w
                + v.x*v.x + v.y*v.y + v.z*v.z + v.w*v.w;
        }
        s  += __shfl_xor(s, 16);  s  += __shfl_xor(s, 32);
        s2 += __shfl_xor(s2, 16); s2 += __shfl_xor(s2, 32);
        if (q4 == 0) { sst[w * 16 + lr] = s; sst2[w * 16 + lr] = s2; }
        __syncthreads();
        float st = sst[lr] + sst[16 + lr] + sst[32 + lr] + sst[48 + lr];
        float st2 = sst2[lr] + sst2[16 + lr] + sst2[32 + lr] + sst2[48 + lr];
        mean = st * (1.0f / (float)K);
        float var = st2 * (1.0f / (float)K) - mean * mean;
        rstd = rsqrtf(var + 1e-5f);
    }

    const h16* arow16 = nullptr;
    if (useA2)       arow16 = A2_16 + (size_t)row * 512 + q4 * 8;
    else if (!LNA)   arow16 = A16 + (size_t)row * lda + q4 * 8;

    // hoisted B fragment bases: per ct, address = base + ks * 2048 halfs
    const h16* wbase[CTN];
#pragma unroll
    for (int ct = 0; ct < CTN; ct++) {
        int tct = (n0 >> 4) + ct;
        wbase[ct] = Wswz + (((size_t)(tct >> 2) * K32 * 4 + (tct & 3)) * 64 + l) * 8;
    }

    f32x4 acc[CTN];
#pragma unroll
    for (int ct = 0; ct < CTN; ct++) acc[ct] = (f32x4){0.f, 0.f, 0.f, 0.f};

    bool wrln = LNA && !useA2 && (bx == 0) && lnout;

#pragma unroll 4
    for (int ks = ks0; ks < ks0 + KQ; ks++) {
        half8 a;
        if (LNA && !useA2) {
            float4 u = *(const float4*)(arow32 + ks * 32);
            float4 v = *(const float4*)(arow32 + ks * 32 + 4);
            float4 g0 = *(const float4*)(lng + ks * 32 + q4 * 8);
            float4 g1 = *(const float4*)(lng + ks * 32 + q4 * 8 + 4);
            float4 b0 = *(const float4*)(lnb + ks * 32 + q4 * 8);
            float4 b1 = *(const float4*)(lnb + ks * 32 + q4 * 8 + 4);
            float4 o0, o1;
            o0.x = (u.x - mean) * rstd * g0.x + b0.x;
            o0.y = (u.y - mean) * rstd * g0.y + b0.y;
            o0.z = (u.z - mean) * rstd * g0.z + b0.z;
            o0.w = (u.w - mean) * rstd * g0.w + b0.w;
            o1.x = (v.x - mean) * rstd * g1.x + b1.x;
            o1.y = (v.y - mean) * rstd * g1.y + b1.y;
            o1.z = (v.z - mean) * rstd * g1.z + b1.z;
            o1.w = (v.w - mean) * rstd * g1.w + b1.w;
            if (wrln) {
                *(float4*)(lnout + (size_t)row * K + ks * 32 + q4 * 8)     = o0;
                *(float4*)(lnout + (size_t)row * K + ks * 32 + q4 * 8 + 4) = o1;
            }
            a = pack8(o0, o1);
        } else if (NSUM == 1) {
            a = *(const half8*)(arow16 + (size_t)ks * 32);
        } else {
            float s[8] = {0.f, 0.f, 0.f, 0.f, 0.f, 0.f, 0.f, 0.f};
#pragma unroll
            for (int j = 0; j < NSUM; j++) {
                half8 tt = *(const half8*)(arow16 + (size_t)j * sumStride + ks * 32);
#pragma unroll
                for (int e = 0; e < 8; e++) s[e] += (float)tt[e];
            }
#pragma unroll
            for (int e = 0; e < 8; e++) a[e] = (h16)s[e];
        }
#pragma unroll
        for (int ct = 0; ct < CTN; ct++) {
            half8 bfr = *(const half8*)(wbase[ct] + (size_t)ks * 2048);
            acc[ct] = __builtin_amdgcn_mfma_f32_16x16x32_f16(a, bfr, acc[ct], 0, 0, 0);
        }
    }

#pragma unroll
    for (int ct = 0; ct < CTN; ct++)
        *(f32x4*)&redu[(size_t)(w * CTN + ct) * 256 + l * 4] = acc[ct];
    __syncthreads();

    if (w < CTN) {
        int ct = w;
        f32x4 sum = *(const f32x4*)&redu[(size_t)ct * 256 + l * 4];
#pragma unroll
        for (int w2 = 1; w2 < 4; w2++) {
            f32x4 tt = *(const f32x4*)&redu[(size_t)(w2 * CTN + ct) * 256 + l * 4];
            sum[0] += tt[0]; sum[1] += tt[1]; sum[2] += tt[2]; sum[3] += tt[3];
        }
        int n = n0 + ct * 16 + lr;
        float bv;
        if (B1) { int sec = n >> 9, ni = n & 511;
                  bv = (sec == 0) ? B0[ni] : (sec == 1 ? B1[ni] : B2s[ni]); }
        else bv = B0[n];
#pragma unroll
        for (int r = 0; r < 4; r++) {
            int m = m0 + q4 * 4 + r;
            float v = sum[r] + bv;
            if (act) v = fmaxf(v, 0.f);
            if (R) v += R[(size_t)m * ldr + n];
            if (C32) C32[(size_t)m * ldc + n] = v;
            if (C16) C16[(size_t)m * ldc + n] = (h16)v;
        }
    }
}

// ---------------------------------------------------------------------------
// Head output: out[q][n] = act( hid16_row . w2_row + b ), into d_out.
// ---------------------------------------------------------------------------
__global__ __launch_bounds__(64) void heads2_k(const h16* __restrict__ hid16,
                                               const float* __restrict__ w2m, const float* __restrict__ b2m,
                                               const float* __restrict__ w2t, const float* __restrict__ b2t,
                                               const float* __restrict__ w2a, const float* __restrict__ b2a,
                                               const float* __restrict__ pmin, const float* __restrict__ pmax,
                                               float* __restrict__ out)
{
    int q = blockIdx.x, n = blockIdx.y, lane = threadIdx.x;
    const float* wr; float bv; int mode, sect;
    if (n < 11)      { sect = 0; wr = w2m + n * 512;        bv = b2m[n];      mode = 0; }
    else if (n < 21) { sect = 1; wr = w2t + (n - 11) * 512; bv = b2t[n - 11]; mode = 1; }
    else             { sect = 2; wr = w2a + (n - 21) * 512; bv = b2a[n - 21]; mode = 2; }
    half8 hv = *(const half8*)(hid16 + q * 1536 + sect * 512 + lane * 8);
    const float4* w4 = (const float4*)(wr + lane * 8);
    float4 c0 = w4[0], c1 = w4[1];
    float acc = (float)hv[0] * c0.x + (float)hv[1] * c0.y
              + (float)hv[2] * c0.z + (float)hv[3] * c0.w
              + (float)hv[4] * c1.x + (float)hv[5] * c1.y
              + (float)hv[6] * c1.z + (float)hv[7] * c1.w;
    for (int off = 32; off; off >>= 1) acc += __shfl_xor(acc, off);
    if (lane == 0) {
        float v = acc + bv;
        if (mode == 0)      v = (1.0f / (1.0f + __expf(-v))) * (pmax[n] - pmin[n]) + pmin[n];
        else if (mode == 2) v = 1.0f / (1.0f + __expf(-v));
        out[q * 24 + n] = v;
    }
}

// ---------------------------------------------------------------------------
// MHA core on packed qkv (128 x 1536 = [Q|K|V] fp32), fp16 output.
// ---------------------------------------------------------------------------
__global__ __launch_bounds__(256) void attn_k(const float* __restrict__ qkv,
                                              h16* __restrict__ out16)
{
    __shared__ float KVl[128 * 68];
    __shared__ float Ql[32 * 68];
    __shared__ float Pl[32 * 128];
    int h = blockIdx.x >> 2, chunk = blockIdx.x & 3;
    int tid = threadIdx.x;

    for (int l = tid; l < 2048; l += 256) {
        int row = l >> 4, c4 = (l & 15) * 4;
        float4 v = *(const float4*)&qkv[row * 1536 + 512 + h * 64 + c4];
        *(float4*)&KVl[row * 68 + c4] = v;
    }
    for (int l = tid; l < 512; l += 256) {
        int row = l >> 4, c4 = (l & 15) * 4;
        float4 v = *(const float4*)&qkv[(chunk * 32 + row) * 1536 + h * 64 + c4];
        *(float4*)&Ql[row * 68 + c4] = v;
    }
    __syncthreads();

    int w = tid >> 6, j = tid & 63;
    for (int r8 = 0; r8 < 8; r8++) {
        int lr = w * 8 + r8;
        float s0 = 0.f, s1 = 0.f;
#pragma unroll
        for (int k4 = 0; k4 < 64; k4 += 4) {
            float4 qv  = *(const float4*)&Ql[lr * 68 + k4];
            float4 k0v = *(const float4*)&KVl[j * 68 + k4];
            float4 k1v = *(const float4*)&KVl[(j + 64) * 68 + k4];
            s0 += qv.x * k0v.x + qv.y * k0v.y + qv.z * k0v.z + qv.w * k0v.w;
            s1 += qv.x * k1v.x + qv.y * k1v.y + qv.z * k1v.z + qv.w * k1v.w;
        }
        s0 *= 0.125f; s1 *= 0.125f;
        float m = fmaxf(s0, s1);
        for (int off = 32; off; off >>= 1) m = fmaxf(m, __shfl_xor(m, off));
        float e0 = __expf(s0 - m), e1 = __expf(s1 - m);
        float sm = e0 + e1;
        for (int off = 32; off; off >>= 1) sm += __shfl_xor(sm, off);
        float inv = 1.0f / sm;
        Pl[lr * 128 + j]      = e0 * inv;
        Pl[lr * 128 + j + 64] = e1 * inv;
    }
    __syncthreads();

    for (int l = tid; l < 2048; l += 256) {
        int row = l >> 4, c4 = (l & 15) * 4;
        float4 v = *(const float4*)&qkv[row * 1536 + 1024 + h * 64 + c4];
        KVl[(c4 + 0) * 132 + row] = v.x;
        KVl[(c4 + 1) * 132 + row] = v.y;
        KVl[(c4 + 2) * 132 + row] = v.z;
        KVl[(c4 + 3) * 132 + row] = v.w;
    }
    __syncthreads();

    int d = tid & 63, w2 = tid >> 6;
    for (int r8 = 0; r8 < 8; r8++) {
        int lr = w2 * 8 + r8;
        float o = 0.f;
#pragma unroll
        for (int j4 = 0; j4 < 128; j4 += 4) {
            float4 pv = *(const float4*)&Pl[lr * 128 + j4];
            float4 vv = *(const float4*)&KVl[d * 132 + j4];
            o += pv.x * vv.x + pv.y * vv.y + pv.z * vv.z + pv.w * vv.w;
        }
        out16[(chunk * 32 + lr) * 512 + h * 64 + d] = (h16)o;
    }
}

// ---------------------------------------------------------------------------
// Gather: grid (128 queries, 6 cams). Compacted taps; fp16 slab out.
// ---------------------------------------------------------------------------
__device__ __forceinline__ float bflo(unsigned u) {
    union { unsigned i; float f; } c; c.i = u << 16; return c.f;
}
__device__ __forceinline__ float bfhi(unsigned u) {
    union { unsigned i; float f; } c; c.i = u & 0xffff0000u; return c.f;
}

__global__ __launch_bounds__(256) void gather_k(const bf16* __restrict__ ft,
                                                const float* __restrict__ proj,
                                                const float* __restrict__ preds,
                                                h16* __restrict__ agg16)
{
    __shared__ float mo[11];
    __shared__ int   goff[384];
    __shared__ float gw[384];
    __shared__ int   cnt;
    __shared__ float part[8][256];
    int n = blockIdx.x, cam = blockIdx.y, tid = threadIdx.x;
    if (tid == 0) cnt = 0;
    if (tid < 11) mo[tid] = preds[n * 24 + tid];
    __syncthreads();

    if (tid < 96) {
        int p = tid;
        float dd0 = mo[8], dd1 = mo[9], dd2 = mo[10];
        float c0 = mo[0], c1 = mo[1], c2 = mo[2];
        float sy, cy;
        sincosf(mo[7], &sy, &cy);
        int face = p >> 4, axis = face >> 1;
        float sgn = (face & 1) ? 0.5f : -0.5f;
        float offi = -0.4f + (float)((p >> 2) & 3) * (0.8f / 3.0f);
        float offj = -0.4f + (float)(p & 3) * (0.8f / 3.0f);
        float t0, t1, t2;
        if (axis == 0)      { t0 = sgn;  t1 = offi; t2 = offj; }
        else if (axis == 1) { t0 = offi; t1 = sgn;  t2 = offj; }
        else                { t0 = offi; t1 = offj; t2 = sgn;  }
        float px = t0 * dd0, py = t1 * dd1, pz = t2 * dd2;
        float X = px * cy - py * sy + c0;
        float Y = px * sy + py * cy + c1;
        float Z = pz + c2;
        const float* P = proj + cam * 12;
        float cu = P[0] * X + P[1] * Y + P[2] * Z + P[3];
        float cv = P[4] * X + P[5] * Y + P[6] * Z + P[7];
        float cz = P[8] * X + P[9] * Y + P[10] * Z + P[11];
        float zs = (fabsf(cz) > 1e-6f) ? cz : 1e-6f;
        float u = cu / zs, v = cv / zs;
        bool front = cz > 0.0f;
        float u0 = floorf(u), v0 = floorf(v);
        float du = u - u0, dv = v - v0;
        float us[4] = {u0, u0 + 1.0f, u0, u0 + 1.0f};
        float vs[4] = {v0, v0, v0 + 1.0f, v0 + 1.0f};
        float wt[4] = {(1.0f - du) * (1.0f - dv), du * (1.0f - dv),
                       (1.0f - du) * dv, du * dv};
        int   myoff[4]; float myw[4]; int k = 0;
#pragma unroll
        for (int t = 0; t < 4; t++) {
            bool ok = front && (us[t] >= 0.0f) && (us[t] <= 119.0f)
                            && (vs[t] >= 0.0f) && (vs[t] <= 47.0f)
                            && (wt[t] > 0.0f);
            if (ok) {
                myoff[k] = ((int)vs[t] * IMW + (int)us[t]) * FD;
                myw[k]   = wt[t];
                k++;
            }
        }
        if (k) {
            int base = atomicAdd(&cnt, k);
            for (int s = 0; s < k; s++) { goff[base + s] = myoff[s]; gw[base + s] = myw[s]; }
        }
    }
    __syncthreads();
    int C = cnt;
    h16* slab = agg16 + (size_t)cam * 32768 + n * 256;
    if (C == 0) { slab[tid] = (h16)0.f; return; }

    int g8  = (tid & 31) * 8;
    int row = tid >> 5;
    const bf16* fb = ft + (size_t)cam * HW * FD + g8;
    float acc[8] = {0.f, 0.f, 0.f, 0.f, 0.f, 0.f, 0.f, 0.f};
    for (int e = row; e < C; e += 8) {
        float w = gw[e];
        uint4 rv = *(const uint4*)(fb + goff[e]);
        acc[0] += w * bflo(rv.x); acc[1] += w * bfhi(rv.x);
        acc[2] += w * bflo(rv.y); acc[3] += w * bfhi(rv.y);
        acc[4] += w * bflo(rv.z); acc[5] += w * bfhi(rv.z);
        acc[6] += w * bflo(rv.w); acc[7] += w * bfhi(rv.w);
    }
#pragma unroll
    for (int j = 0; j < 8; j++) part[row][g8 + j] = acc[j];
    __syncthreads();
    float s = 0.f;
#pragma unroll
    for (int r = 0; r < 8; r++) s += part[r][tid];
    slab[tid] = (h16)(s * (1.0f / 576.0f));
}

// ---------------------------------------------------------------------------
extern "C" void kernel_launch(void* const* d_in, const int* in_sizes, int n_in,
                              void* d_out, int out_size, void* d_ws, size_t ws_size,
                              hipStream_t stream)
{
    const float* features  = (const float*)d_in[0];
    const float* proj      = (const float*)d_in[1];
    const float* queries0  = (const float*)d_in[3];
    const float* pmin      = (const float*)d_in[4];
    const float* pmax      = (const float*)d_in[5];
    const float* motion_w1 = (const float*)d_in[6];
    const float* motion_b1 = (const float*)d_in[7];
    const float* motion_w2 = (const float*)d_in[8];
    const float* motion_b2 = (const float*)d_in[9];
    const float* type_w1   = (const float*)d_in[10];
    const float* type_b1   = (const float*)d_in[11];
    const float* type_w2   = (const float*)d_in[12];
    const float* type_b2   = (const float*)d_in[13];
    const float* attr_w1   = (const float*)d_in[14];
    const float* attr_b1   = (const float*)d_in[15];
    const float* attr_w2   = (const float*)d_in[16];
    const float* attr_b2   = (const float*)d_in[17];
    const float* fmlp_w1   = (const float*)d_in[18];
    const float* fmlp_b1   = (const float*)d_in[19];
    const float* fmlp_w2   = (const float*)d_in[20];
    const float* fmlp_b2   = (const float*)d_in[21];
    const float* sa_in_w   = (const float*)d_in[22];
    const float* sa_in_b   = (const float*)d_in[23];
    const float* sa_out_w  = (const float*)d_in[24];
    const float* sa_out_b  = (const float*)d_in[25];
    const float* fa_in_w   = (const float*)d_in[26];
    const float* fa_in_b   = (const float*)d_in[27];
    const float* fa_out_w  = (const float*)d_in[28];
    const float* fa_out_b  = (const float*)d_in[29];
    const float* ffn_w1    = (const float*)d_in[30];
    const float* ffn_b1    = (const float*)d_in[31];
    const float* ffn_w2    = (const float*)d_in[32];
    const float* ffn_b2    = (const float*)d_in[33];
    const float* ln1_g     = (const float*)d_in[34];
    const float* ln1_b     = (const float*)d_in[35];
    const float* ln2_g     = (const float*)d_in[36];
    const float* ln2_b     = (const float*)d_in[37];
    const float* ln3_g     = (const float*)d_in[38];
    const float* ln3_b     = (const float*)d_in[39];
    float* out = (float*)d_out;

    // ---- workspace ----
    char* p = (char*)d_ws;
    bf16* feat_t = (bf16*)p;   p += (size_t)NC * HW * FD * 2;        // 17.7 MB
    h16* swz     = (h16*)p;    p += (size_t)51456 * 512 * 2;         // 52.7 MB
    h16* q016    = (h16*)p;    p += 65536 * 2;
    h16* hid16   = (h16*)p;    p += 196608 * 2;
    h16* agg16   = (h16*)p;    p += 196608 * 2;
    h16* fmlph16 = (h16*)p;    p += 65536 * 2;
    h16* feath16 = (h16*)p;    p += 65536 * 2;
    h16* attnb16 = (h16*)p;    p += 65536 * 2;
    h16* ffnh16  = (h16*)p;    p += 262144 * 2;
    h16* qn16    = (h16*)p;    p += 65536 * 2;
    float* qkv   = (float*)p;  p += 196608 * 4;
    float* lnx   = (float*)p;  p += 65536 * 4;
    float* x1    = (float*)p;  p += 65536 * 4;
    float* x2    = (float*)p;  p += 65536 * 4;
    float* qn32  = (float*)p;  p += 65536 * 4;

    // ---- one-time prep ----
    SwzDesc sd;
    const float* srcs[11] = {motion_w1, type_w1, attr_w1, fmlp_w1, fmlp_w2,
                             sa_in_w, sa_out_w, fa_in_w, fa_out_w, ffn_w1, ffn_w2};
    int Ks[11]    = {512, 512, 512, 256, 512, 512, 512, 512, 512, 512, 2048};
    int tiles[11] = {512, 512, 512, 256, 512, 9216, 3072, 9216, 3072, 12288, 12288};
    unsigned int cumT = 0, cumC = 0;
    for (int i = 0; i < 11; i++) {
        sd.src[i] = srcs[i]; sd.K[i] = Ks[i];
        sd.tileStart[i] = cumT; sd.chunkStart[i] = cumC;
        cumT += tiles[i]; cumC += tiles[i] >> 3;
    }
    sd.chunkStart[11] = cumC;   // 6432

    swizzle3_k<<<6432, 256, 0, stream>>>(sd, swz);
    cvt16_k<<<256, 256, 0, stream>>>(queries0, q016, 65536);
    transpose_feat_k<<<dim3(180, 8, 6), dim3(32, 8), 0, stream>>>(features, feat_t);

    // swizzled weight bases (halfs)
    const h16* sw_heads = swz;                      // motion|type|attr, N=1536,K=512
    const h16* sw_fmlp1 = swz + 786432;             // K=256
    const h16* sw_fmlp2 = swz + 917504;
    const h16* sw_sain  = swz + 1179648;            // + i*786432
    const h16* sw_saout = swz + 5898240;            // + i*262144
    const h16* sw_fain  = swz + 7471104;            // + i*786432
    const h16* sw_faout = swz + 12189696;           // + i*262144
    const h16* sw_ffn1  = swz + 13762560;           // + i*1048576
    const h16* sw_ffn2  = swz + 20054016;           // + i*1048576

    const h16*   q16 = q016;
    const float* q32 = queries0;

    for (int i = 0; i < 6; i++) {
        // prediction heads
        gemm_sk4<2, 1, false, false><<<dim3(48, 8), 256, 0, stream>>>(
            q16, 512, 0, nullptr, nullptr, nullptr, nullptr, nullptr, 0,
            sw_heads, motion_b1, type_b1, attr_b1, nullptr, 0,
            nullptr, hid16, 1536, 512, 1);
        heads2_k<<<dim3(128, 24), 64, 0, stream>>>(hid16, motion_w2, motion_b2,
                                                   type_w2, type_b2, attr_w2, attr_b2,
                                                   pmin, pmax, out + i * 3072);
        if (i == 5) break;

        // feature gather + feature MLP
        gather_k<<<dim3(128, 6), 256, 0, stream>>>(feat_t, proj, out + i * 3072, agg16);
        gemm_sk4<1, 6, false, false><<<dim3(32, 8), 256, 0, stream>>>(
            agg16, 256, 32768, nullptr, nullptr, nullptr, nullptr, nullptr, 0,
            sw_fmlp1, fmlp_b1, nullptr, nullptr, nullptr, 0,
            nullptr, fmlph16, 512, 256, 1);
        gemm_sk4<1, 1, false, false><<<dim3(32, 8), 256, 0, stream>>>(
            fmlph16, 512, 0, nullptr, nullptr, nullptr, nullptr, nullptr, 0,
            sw_fmlp2, fmlp_b2, nullptr, nullptr, nullptr, 0,
            nullptr, feath16, 512, 512, 0);

        // self-attention (LN1 fused into qkv projection)
        gemm_sk4<2, 1, false, true><<<dim3(48, 8), 256, 0, stream>>>(
            nullptr, 0, 0, q32, ln1_g + i * 512, ln1_b + i * 512, lnx, nullptr, 0,
            sw_sain + (size_t)i * 786432, sa_in_b + i * 1536, nullptr, nullptr,
            nullptr, 0, qkv, nullptr, 1536, 512, 0);
        attn_k<<<32, 256, 0, stream>>>(qkv, attnb16);
        gemm_sk4<1, 1, false, false><<<dim3(32, 8), 256, 0, stream>>>(
            attnb16, 512, 0, nullptr, nullptr, nullptr, nullptr, nullptr, 0,
            sw_saout + (size_t)i * 262144, sa_out_b + i * 512, nullptr, nullptr,
            lnx, 512, x1, nullptr, 512, 512, 0);

        // cross-attention (LN2 fused; kv side reads feath16 via A2 switch)
        gemm_sk4<2, 1, true, true><<<dim3(48, 8), 256, 0, stream>>>(
            nullptr, 0, 0, x1, ln2_g + i * 512, ln2_b + i * 512, lnx, feath16, 16,
            sw_fain + (size_t)i * 786432, fa_in_b + i * 1536, nullptr, nullptr,
            nullptr, 0, qkv, nullptr, 1536, 512, 0);
        attn_k<<<32, 256, 0, stream>>>(qkv, attnb16);
        gemm_sk4<1, 1, false, false><<<dim3(32, 8), 256, 0, stream>>>(
            attnb16, 512, 0, nullptr, nullptr, nullptr, nullptr, nullptr, 0,
            sw_faout + (size_t)i * 262144, fa_out_b + i * 512, nullptr, nullptr,
            lnx, 512, x2, nullptr, 512, 512, 0);

        // FFN (LN3 fused into ffn1)
        gemm_sk4<2, 1, false, true><<<dim3(64, 8), 256, 0, stream>>>(
            nullptr, 0, 0, x2, ln3_g + i * 512, ln3_b + i * 512, lnx, nullptr, 0,
            sw_ffn1 + (size_t)i * 1048576, ffn_b1 + i * 2048, nullptr, nullptr,
            nullptr, 0, nullptr, ffnh16, 2048, 512, 1);
        gemm_sk4<1, 1, false, false><<<dim3(32, 8), 256, 0, stream>>>(
            ffnh16, 2048, 0, nullptr, nullptr, nullptr, nullptr, nullptr, 0,
            sw_ffn2 + (size_t)i * 1048576, ffn_b2 + i * 512, nullptr, nullptr,
            lnx, 512, qn32, qn16, 512, 2048, 0);

        q16 = qn16;
        q32 = qn32;
    }
}

// Round 3
// 815.094 us; speedup vs baseline: 1.1485x; 1.0594x over previous
//
#include <hip/hip_runtime.h>
#include <hip/hip_bf16.h>

typedef __hip_bfloat16 bf16;
typedef _Float16 h16;
typedef __attribute__((ext_vector_type(8))) _Float16 half8;
typedef __attribute__((ext_vector_type(4))) _Float16 half4;
typedef __attribute__((ext_vector_type(4))) float f32x4;

#define NQ 128
#define HD 512
#define FD 256
#define NC 6
#define IMH 48
#define IMW 120
#define HW 5760   // 48*120

__device__ __forceinline__ half8 pack8(float4 x, float4 y) {
    half8 h;
    h[0] = (h16)x.x; h[1] = (h16)x.y; h[2] = (h16)x.z; h[3] = (h16)x.w;
    h[4] = (h16)y.x; h[5] = (h16)y.y; h[6] = (h16)y.z; h[7] = (h16)y.w;
    return h;
}

// ---------------------------------------------------------------------------
// Device bodies (shared-memory passed in so kernels can be horizontally fused)
// ---------------------------------------------------------------------------

// ---- feature transpose body: (NC, FD, HW) f32 -> (NC, HW, FD) bf16 ----
__device__ __forceinline__ void transpose_body(int bx, int by, int cam,
                                               int tx, int ty, float* tile,
                                               const float* __restrict__ f,
                                               bf16* __restrict__ ft)
{
    int hw0 = bx * 32, fd0 = by * 32;
    const float* fb = f + (size_t)cam * FD * HW;
    for (int r = ty; r < 32; r += 8)
        tile[r * 33 + tx] = fb[(size_t)(fd0 + r) * HW + hw0 + tx];
    __syncthreads();
    bf16* fo = ft + (size_t)cam * HW * FD;
    for (int r = ty; r < 32; r += 8)
        fo[(size_t)(hw0 + r) * FD + fd0 + tx] = __float2bfloat16(tile[tx * 33 + r]);
}

// ---- weight swizzle v3 body (verified round 2: 0 bank conflicts) ----
struct SwzDesc {
    const float* src[11];
    unsigned int chunkStart[12];   // block-id boundaries
    unsigned int tileStart[11];    // dst tile base
    int K[11];
};

__device__ __forceinline__ int lperm(int lane, int ksl) {
    return lane ^ ((lane >> 4) & 3) ^ (ksl << 2);
}

__device__ __forceinline__ void swizzle_body(int bid, int t, h16* fbuf,
                                             const SwzDesc& d, h16* __restrict__ dst)
{
    int w = 0;
    while (bid >= (int)d.chunkStart[w + 1]) w++;
    int local = bid - (int)d.chunkStart[w];
    int Kk = d.K[w];
    int kc = Kk >> 6;              // 64-col chunks per row group
    int n64 = local / kc, kchunk = local - n64 * kc;

    int rr  = t >> 4;              // 0..15 row within pass-group
    int cb  = (t & 15) * 4;        // 0..60, 16 lanes contiguous = 256B segment
    int ksl = (t >> 3) & 1;        // cb>>5
    int kk  = cb & 31;
    int laneb = ((kk >> 3) << 4) + rr;
    int elemB = (kk & 7) * 2;
    const float* sbase = d.src[w] + (size_t)(n64 * 64 + rr) * Kk + kchunk * 64 + cb;
#pragma unroll
    for (int rp = 0; rp < 4; rp++) {
        float4 u = *(const float4*)(sbase + (size_t)rp * 16 * Kk);
        int tile8 = ksl * 4 + rp;
        int l2 = lperm(laneb, ksl);
        half4* fp = (half4*)((char*)fbuf + tile8 * 1024 + l2 * 16 + elemB);
        half4 hv; hv[0] = (h16)u.x; hv[1] = (h16)u.y; hv[2] = (h16)u.z; hv[3] = (h16)u.w;
        *fp = hv;
    }
    __syncthreads();

    int K32 = Kk >> 5;
#pragma unroll
    for (int i = 0; i < 2; i++) {
        int hidx = t + i * 256;
        int tl = hidx >> 6, within = hidx & 63;
        int ksl2 = tl >> 2, ctt = tl & 3;
        int l2 = lperm(within, ksl2);
        size_t tileg = (size_t)d.tileStart[w]
                     + ((size_t)n64 * K32 + (kchunk * 2 + ksl2)) * 4 + ctt;
        *(half8*)(dst + tileg * 512 + within * 8) =
            *(const half8*)((const char*)fbuf + tl * 1024 + l2 * 16);
    }
}

// ---- split-K-in-block MFMA GEMM body on swizzled fp16 weights ----
template<int CTN, int NSUM, bool A2SW, bool LNA>
__device__ __forceinline__ void gemm_body(int bx, int by, int tid,
    float* redu, float* sst, float* sst2,
    const h16* __restrict__ A16, int lda, int sumStride,
    const float* __restrict__ A32,
    const float* __restrict__ lng, const float* __restrict__ lnb,
    float* __restrict__ lnout,
    const h16* __restrict__ A2_16, int a2Start,
    const h16* __restrict__ Wswz,
    const float* __restrict__ B0, const float* __restrict__ B1, const float* __restrict__ B2s,
    const float* __restrict__ R, int ldr,
    float* __restrict__ C32, h16* __restrict__ C16, int ldc,
    int K, int act)
{
    int w = tid >> 6, l = tid & 63;
    int lr = l & 15, q4 = l >> 4;
    int m0 = by * 16;
    int n0 = bx * 16 * CTN;
    int row = m0 + lr;
    int K32 = K >> 5;
    int KQ = K32 >> 2;
    int ks0 = w * KQ;

    bool useA2 = A2SW && (bx >= a2Start);

    const float* arow32 = nullptr;
    float mean = 0.f, rstd = 1.f;
    if (LNA && !useA2) {
        arow32 = A32 + (size_t)row * K + q4 * 8;
        float s = 0.f, s2 = 0.f;
        for (int ks = ks0; ks < ks0 + KQ; ks++) {
            float4 u = *(const float4*)(arow32 + ks * 32);
            float4 v = *(const float4*)(arow32 + ks * 32 + 4);
            s  += u.x + u.y + u.z + u.w + v.x + v.y + v.z + v.w;
            s2 += u.x*u.x + u.y*u.y + u.z*u.z + u.w*u.w
                + v.x*v.x + v.y*v.y + v.z*v.z + v.w*v.w;
        }
        s  += __shfl_xor(s, 16);  s  += __shfl_xor(s, 32);
        s2 += __shfl_xor(s2, 16); s2 += __shfl_xor(s2, 32);
        if (q4 == 0) { sst[w * 16 + lr] = s; sst2[w * 16 + lr] = s2; }
        __syncthreads();
        float st = sst[lr] + sst[16 + lr] + sst[32 + lr] + sst[48 + lr];
        float st2 = sst2[lr] + sst2[16 + lr] + sst2[32 + lr] + sst2[48 + lr];
        mean = st * (1.0f / (float)K);
        float var = st2 * (1.0f / (float)K) - mean * mean;
        rstd = rsqrtf(var + 1e-5f);
    }

    const h16* arow16 = nullptr;
    if (useA2)       arow16 = A2_16 + (size_t)row * 512 + q4 * 8;
    else if (!LNA)   arow16 = A16 + (size_t)row * lda + q4 * 8;

    const h16* wbase[CTN];
#pragma unroll
    for (int ct = 0; ct < CTN; ct++) {
        int tct = (n0 >> 4) + ct;
        wbase[ct] = Wswz + (((size_t)(tct >> 2) * K32 * 4 + (tct & 3)) * 64 + l) * 8;
    }

    f32x4 acc[CTN];
#pragma unroll
    for (int ct = 0; ct < CTN; ct++) acc[ct] = (f32x4){0.f, 0.f, 0.f, 0.f};

    bool wrln = LNA && !useA2 && (bx == 0) && lnout;

#pragma unroll 4
    for (int ks = ks0; ks < ks0 + KQ; ks++) {
        half8 a;
        if (LNA && !useA2) {
            float4 u = *(const float4*)(arow32 + ks * 32);
            float4 v = *(const float4*)(arow32 + ks * 32 + 4);
            float4 g0 = *(const float4*)(lng + ks * 32 + q4 * 8);
            float4 g1 = *(const float4*)(lng + ks * 32 + q4 * 8 + 4);
            float4 b0 = *(const float4*)(lnb + ks * 32 + q4 * 8);
            float4 b1 = *(const float4*)(lnb + ks * 32 + q4 * 8 + 4);
            float4 o0, o1;
            o0.x = (u.x - mean) * rstd * g0.x + b0.x;
            o0.y = (u.y - mean) * rstd * g0.y + b0.y;
            o0.z = (u.z - mean) * rstd * g0.z + b0.z;
            o0.w = (u.w - mean) * rstd * g0.w + b0.w;
            o1.x = (v.x - mean) * rstd * g1.x + b1.x;
            o1.y = (v.y - mean) * rstd * g1.y + b1.y;
            o1.z = (v.z - mean) * rstd * g1.z + b1.z;
            o1.w = (v.w - mean) * rstd * g1.w + b1.w;
            if (wrln) {
                *(float4*)(lnout + (size_t)row * K + ks * 32 + q4 * 8)     = o0;
                *(float4*)(lnout + (size_t)row * K + ks * 32 + q4 * 8 + 4) = o1;
            }
            a = pack8(o0, o1);
        } else if (NSUM == 1) {
            a = *(const half8*)(arow16 + (size_t)ks * 32);
        } else {
            float s[8] = {0.f, 0.f, 0.f, 0.f, 0.f, 0.f, 0.f, 0.f};
#pragma unroll
            for (int j = 0; j < NSUM; j++) {
                half8 tt = *(const half8*)(arow16 + (size_t)j * sumStride + ks * 32);
#pragma unroll
                for (int e = 0; e < 8; e++) s[e] += (float)tt[e];
            }
#pragma unroll
            for (int e = 0; e < 8; e++) a[e] = (h16)s[e];
        }
#pragma unroll
        for (int ct = 0; ct < CTN; ct++) {
            half8 bfr = *(const half8*)(wbase[ct] + (size_t)ks * 2048);
            acc[ct] = __builtin_amdgcn_mfma_f32_16x16x32_f16(a, bfr, acc[ct], 0, 0, 0);
        }
    }

#pragma unroll
    for (int ct = 0; ct < CTN; ct++)
        *(f32x4*)&redu[(size_t)(w * CTN + ct) * 256 + l * 4] = acc[ct];
    __syncthreads();

    if (w < CTN) {
        int ct = w;
        f32x4 sum = *(const f32x4*)&redu[(size_t)ct * 256 + l * 4];
#pragma unroll
        for (int w2 = 1; w2 < 4; w2++) {
            f32x4 tt = *(const f32x4*)&redu[(size_t)(w2 * CTN + ct) * 256 + l * 4];
            sum[0] += tt[0]; sum[1] += tt[1]; sum[2] += tt[2]; sum[3] += tt[3];
        }
        int n = n0 + ct * 16 + lr;
        float bv;
        if (B1) { int sec = n >> 9, ni = n & 511;
                  bv = (sec == 0) ? B0[ni] : (sec == 1 ? B1[ni] : B2s[ni]); }
        else bv = B0[n];
#pragma unroll
        for (int r = 0; r < 4; r++) {
            int m = m0 + q4 * 4 + r;
            float v = sum[r] + bv;
            if (act) v = fmaxf(v, 0.f);
            if (R) v += R[(size_t)m * ldr + n];
            if (C32) C32[(size_t)m * ldc + n] = v;
            if (C16) C16[(size_t)m * ldc + n] = (h16)v;
        }
    }
}

// ---- head output body: one wave per (q, n) ----
__device__ __forceinline__ void heads2_body(int q, int n, int lane,
    const h16* __restrict__ hid16,
    const float* __restrict__ w2m, const float* __restrict__ b2m,
    const float* __restrict__ w2t, const float* __restrict__ b2t,
    const float* __restrict__ w2a, const float* __restrict__ b2a,
    const float* __restrict__ pmin, const float* __restrict__ pmax,
    float* __restrict__ out)
{
    const float* wr; float bv; int mode, sect;
    if (n < 11)      { sect = 0; wr = w2m + n * 512;        bv = b2m[n];      mode = 0; }
    else if (n < 21) { sect = 1; wr = w2t + (n - 11) * 512; bv = b2t[n - 11]; mode = 1; }
    else             { sect = 2; wr = w2a + (n - 21) * 512; bv = b2a[n - 21]; mode = 2; }
    half8 hv = *(const half8*)(hid16 + q * 1536 + sect * 512 + lane * 8);
    const float4* w4 = (const float4*)(wr + lane * 8);
    float4 c0 = w4[0], c1 = w4[1];
    float acc = (float)hv[0] * c0.x + (float)hv[1] * c0.y
              + (float)hv[2] * c0.z + (float)hv[3] * c0.w
              + (float)hv[4] * c1.x + (float)hv[5] * c1.y
              + (float)hv[6] * c1.z + (float)hv[7] * c1.w;
    for (int off = 32; off; off >>= 1) acc += __shfl_xor(acc, off);
    if (lane == 0) {
        float v = acc + bv;
        if (mode == 0)      v = (1.0f / (1.0f + __expf(-v))) * (pmax[n] - pmin[n]) + pmin[n];
        else if (mode == 2) v = 1.0f / (1.0f + __expf(-v));
        out[q * 24 + n] = v;
    }
}

// ---- MHA core body on packed qkv (128 x 1536 = [Q|K|V] fp32) ----
__device__ __forceinline__ void attn_body(int bid, int tid,
                                          float* KVl, float* Ql, float* Pl,
                                          const float* __restrict__ qkv,
                                          h16* __restrict__ out16)
{
    int h = bid >> 2, chunk = bid & 3;

    for (int l = tid; l < 2048; l += 256) {
        int row = l >> 4, c4 = (l & 15) * 4;
        float4 v = *(const float4*)&qkv[row * 1536 + 512 + h * 64 + c4];
        *(float4*)&KVl[row * 68 + c4] = v;
    }
    for (int l = tid; l < 512; l += 256) {
        int row = l >> 4, c4 = (l & 15) * 4;
        float4 v = *(const float4*)&qkv[(chunk * 32 + row) * 1536 + h * 64 + c4];
        *(float4*)&Ql[row * 68 + c4] = v;
    }
    __syncthreads();

    int w = tid >> 6, j = tid & 63;
    for (int r8 = 0; r8 < 8; r8++) {
        int lr = w * 8 + r8;
        float s0 = 0.f, s1 = 0.f;
#pragma unroll
        for (int k4 = 0; k4 < 64; k4 += 4) {
            float4 qv  = *(const float4*)&Ql[lr * 68 + k4];
            float4 k0v = *(const float4*)&KVl[j * 68 + k4];
            float4 k1v = *(const float4*)&KVl[(j + 64) * 68 + k4];
            s0 += qv.x * k0v.x + qv.y * k0v.y + qv.z * k0v.z + qv.w * k0v.w;
            s1 += qv.x * k1v.x + qv.y * k1v.y + qv.z * k1v.z + qv.w * k1v.w;
        }
        s0 *= 0.125f; s1 *= 0.125f;
        float m = fmaxf(s0, s1);
        for (int off = 32; off; off >>= 1) m = fmaxf(m, __shfl_xor(m, off));
        float e0 = __expf(s0 - m), e1 = __expf(s1 - m);
        float sm = e0 + e1;
        for (int off = 32; off; off >>= 1) sm += __shfl_xor(sm, off);
        float inv = 1.0f / sm;
        Pl[lr * 128 + j]      = e0 * inv;
        Pl[lr * 128 + j + 64] = e1 * inv;
    }
    __syncthreads();

    for (int l = tid; l < 2048; l += 256) {
        int row = l >> 4, c4 = (l & 15) * 4;
        float4 v = *(const float4*)&qkv[row * 1536 + 1024 + h * 64 + c4];
        KVl[(c4 + 0) * 132 + row] = v.x;
        KVl[(c4 + 1) * 132 + row] = v.y;
        KVl[(c4 + 2) * 132 + row] = v.z;
        KVl[(c4 + 3) * 132 + row] = v.w;
    }
    __syncthreads();

    int d = tid & 63, w2 = tid >> 6;
    for (int r8 = 0; r8 < 8; r8++) {
        int lr = w2 * 8 + r8;
        float o = 0.f;
#pragma unroll
        for (int j4 = 0; j4 < 128; j4 += 4) {
            float4 pv = *(const float4*)&Pl[lr * 128 + j4];
            float4 vv = *(const float4*)&KVl[d * 132 + j4];
            o += pv.x * vv.x + pv.y * vv.y + pv.z * vv.z + pv.w * vv.w;
        }
        out16[(chunk * 32 + lr) * 512 + h * 64 + d] = (h16)o;
    }
}

// ---------------------------------------------------------------------------
// Kernels
// ---------------------------------------------------------------------------

// prep: swizzle (6432 blocks) + feature transpose (8640) + q0 cvt (256)
__global__ __launch_bounds__(256) void prep_k(SwzDesc d, h16* __restrict__ swz,
                                              const float* __restrict__ feat,
                                              bf16* __restrict__ feat_t,
                                              const float* __restrict__ q0,
                                              h16* __restrict__ q016)
{
    __shared__ char shm[8448];
    int bid = blockIdx.x, t = threadIdx.x;
    if (bid < 6432) {
        swizzle_body(bid, t, (h16*)shm, d, swz);
    } else if (bid < 15072) {
        int tb = bid - 6432;
        transpose_body(tb % 180, (tb / 180) % 8, tb / 1440, t & 31, t >> 5,
                       (float*)shm, feat, feat_t);
    } else {
        int i = (bid - 15072) * 256 + t;
        q016[i] = (h16)q0[i];
    }
}

// standalone GEMM
template<int CTN, int NSUM, bool A2SW, bool LNA>
__global__ __launch_bounds__(256) void gemm_sk4(
    const h16* __restrict__ A16, int lda, int sumStride,
    const float* __restrict__ A32,
    const float* __restrict__ lng, const float* __restrict__ lnb,
    float* __restrict__ lnout,
    const h16* __restrict__ A2_16, int a2Start,
    const h16* __restrict__ Wswz,
    const float* __restrict__ B0, const float* __restrict__ B1, const float* __restrict__ B2s,
    const float* __restrict__ R, int ldr,
    float* __restrict__ C32, h16* __restrict__ C16, int ldc,
    int K, int act)
{
    __shared__ float redu[CTN * 4 * 256];
    __shared__ float sst[64], sst2[64];
    gemm_body<CTN, NSUM, A2SW, LNA>(blockIdx.x, blockIdx.y, threadIdx.x,
        redu, sst, sst2, A16, lda, sumStride, A32, lng, lnb, lnout, A2_16, a2Start,
        Wswz, B0, B1, B2s, R, ldr, C32, C16, ldc, K, act);
}

// standalone heads2 (layer 6)
__global__ __launch_bounds__(64) void heads2_k(const h16* __restrict__ hid16,
                                               const float* __restrict__ w2m, const float* __restrict__ b2m,
                                               const float* __restrict__ w2t, const float* __restrict__ b2t,
                                               const float* __restrict__ w2a, const float* __restrict__ b2a,
                                               const float* __restrict__ pmin, const float* __restrict__ pmax,
                                               float* __restrict__ out)
{
    heads2_body(blockIdx.x, blockIdx.y, threadIdx.x,
                hid16, w2m, b2m, w2t, b2t, w2a, b2a, pmin, pmax, out);
}

// standalone attention (cross-attn slot)
__global__ __launch_bounds__(256) void attn_k(const float* __restrict__ qkv,
                                              h16* __restrict__ out16)
{
    __shared__ float KVl[128 * 68];
    __shared__ float Ql[32 * 68];
    __shared__ float Pl[32 * 128];
    attn_body(blockIdx.x, threadIdx.x, KVl, Ql, Pl, qkv, out16);
}

// D2: heads2 (x>=48, 4 waves = 4 (q,n) pairs per block) || sa_in GEMM (x<48)
__global__ __launch_bounds__(256) void d2_k(
    const float* __restrict__ q32, const float* __restrict__ lng,
    const float* __restrict__ lnb, float* __restrict__ lnx,
    const h16* __restrict__ Wsain, const float* __restrict__ Bsain,
    float* __restrict__ qkv,
    const h16* __restrict__ hid16,
    const float* __restrict__ w2m, const float* __restrict__ b2m,
    const float* __restrict__ w2t, const float* __restrict__ b2t,
    const float* __restrict__ w2a, const float* __restrict__ b2a,
    const float* __restrict__ pmin, const float* __restrict__ pmax,
    float* __restrict__ out)
{
    __shared__ float redu[2 * 4 * 256];
    __shared__ float sst[64], sst2[64];
    int x = blockIdx.x, by = blockIdx.y, tid = threadIdx.x;
    if (x < 48) {
        gemm_body<2, 1, false, true>(x, by, tid, redu, sst, sst2,
            nullptr, 0, 0, q32, lng, lnb, lnx, nullptr, 0,
            Wsain, Bsain, nullptr, nullptr, nullptr, 0,
            qkv, nullptr, 1536, 512, 0);
    } else {
        int p = (((x - 48) * 8 + by) << 2) + (tid >> 6);   // 0..3071
        heads2_body(p / 24, p % 24, tid & 63,
                    hid16, w2m, b2m, w2t, b2t, w2a, b2a, pmin, pmax, out);
    }
}

// D4: fmlp1 GEMM (x<32) || self-attn core (x>=32, slot=(x-32)*8+by)
__global__ __launch_bounds__(256) void d4_k(
    const h16* __restrict__ agg16, const h16* __restrict__ Wf1,
    const float* __restrict__ Bf1, h16* __restrict__ fmlph16,
    const float* __restrict__ qkv, h16* __restrict__ attnb16)
{
    __shared__ float smem[14976];   // attn: KVl 8704 | Ql 2176 | Pl 4096
    int x = blockIdx.x, by = blockIdx.y, tid = threadIdx.x;
    if (x < 32) {
        gemm_body<1, 6, false, false>(x, by, tid, smem, smem + 1024, smem + 1088,
            agg16, 256, 32768, nullptr, nullptr, nullptr, nullptr, nullptr, 0,
            Wf1, Bf1, nullptr, nullptr, nullptr, 0,
            nullptr, fmlph16, 512, 256, 1);
    } else {
        int slot = (x - 32) * 8 + by;   // 0..31
        attn_body(slot, tid, smem, smem + 8704, smem + 10880, qkv, attnb16);
    }
}

// D5: fmlp2 GEMM (x<32) || sa_out GEMM (x>=32)
__global__ __launch_bounds__(256) void d5_k(
    const h16* __restrict__ fmlph16, const h16* __restrict__ Wf2,
    const float* __restrict__ Bf2, h16* __restrict__ feath16,
    const h16* __restrict__ attnb16, const h16* __restrict__ Wso,
    const float* __restrict__ Bso, const float* __restrict__ lnx,
    float* __restrict__ x1)
{
    __shared__ float redu[1024];
    __shared__ float sst[64], sst2[64];
    int x = blockIdx.x, by = blockIdx.y, tid = threadIdx.x;
    if (x < 32) {
        gemm_body<1, 1, false, false>(x, by, tid, redu, sst, sst2,
            fmlph16, 512, 0, nullptr, nullptr, nullptr, nullptr, nullptr, 0,
            Wf2, Bf2, nullptr, nullptr, nullptr, 0,
            nullptr, feath16, 512, 512, 0);
    } else {
        gemm_body<1, 1, false, false>(x - 32, by, tid, redu, sst, sst2,
            attnb16, 512, 0, nullptr, nullptr, nullptr, nullptr, nullptr, 0,
            Wso, Bso, nullptr, nullptr, lnx, 512,
            x1, nullptr, 512, 512, 0);
    }
}

// ---------------------------------------------------------------------------
// Gather: grid (128 queries, 6 cams). Compacted taps; fp16 slab out.
// ---------------------------------------------------------------------------
__device__ __forceinline__ float bflo(unsigned u) {
    union { unsigned i; float f; } c; c.i = u << 16; return c.f;
}
__device__ __forceinline__ float bfhi(unsigned u) {
    union { unsigned i; float f; } c; c.i = u & 0xffff0000u; return c.f;
}

__global__ __launch_bounds__(256) void gather_k(const bf16* __restrict__ ft,
                                                const float* __restrict__ proj,
                                                const float* __restrict__ preds,
                                                h16* __restrict__ agg16)
{
    __shared__ float mo[11];
    __shared__ int   goff[384];
    __shared__ float gw[384];
    __shared__ int   cnt;
    __shared__ float part[8][256];
    int n = blockIdx.x, cam = blockIdx.y, tid = threadIdx.x;
    if (tid == 0) cnt = 0;
    if (tid < 11) mo[tid] = preds[n * 24 + tid];
    __syncthreads();

    if (tid < 96) {
        int p = tid;
        float dd0 = mo[8], dd1 = mo[9], dd2 = mo[10];
        float c0 = mo[0], c1 = mo[1], c2 = mo[2];
        float sy, cy;
        sincosf(mo[7], &sy, &cy);
        int face = p >> 4, axis = face >> 1;
        float sgn = (face & 1) ? 0.5f : -0.5f;
        float offi = -0.4f + (float)((p >> 2) & 3) * (0.8f / 3.0f);
        float offj = -0.4f + (float)(p & 3) * (0.8f / 3.0f);
        float t0, t1, t2;
        if (axis == 0)      { t0 = sgn;  t1 = offi; t2 = offj; }
        else if (axis == 1) { t0 = offi; t1 = sgn;  t2 = offj; }
        else                { t0 = offi; t1 = offj; t2 = sgn;  }
        float px = t0 * dd0, py = t1 * dd1, pz = t2 * dd2;
        float X = px * cy - py * sy + c0;
        float Y = px * sy + py * cy + c1;
        float Z = pz + c2;
        const float* P = proj + cam * 12;
        float cu = P[0] * X + P[1] * Y + P[2] * Z + P[3];
        float cv = P[4] * X + P[5] * Y + P[6] * Z + P[7];
        float cz = P[8] * X + P[9] * Y + P[10] * Z + P[11];
        float zs = (fabsf(cz) > 1e-6f) ? cz : 1e-6f;
        float u = cu / zs, v = cv / zs;
        bool front = cz > 0.0f;
        float u0 = floorf(u), v0 = floorf(v);
        float du = u - u0, dv = v - v0;
        float us[4] = {u0, u0 + 1.0f, u0, u0 + 1.0f};
        float vs[4] = {v0, v0, v0 + 1.0f, v0 + 1.0f};
        float wt[4] = {(1.0f - du) * (1.0f - dv), du * (1.0f - dv),
                       (1.0f - du) * dv, du * dv};
        int   myoff[4]; float myw[4]; int k = 0;
#pragma unroll
        for (int t = 0; t < 4; t++) {
            bool ok = front && (us[t] >= 0.0f) && (us[t] <= 119.0f)
                            && (vs[t] >= 0.0f) && (vs[t] <= 47.0f)
                            && (wt[t] > 0.0f);
            if (ok) {
                myoff[k] = ((int)vs[t] * IMW + (int)us[t]) * FD;
                myw[k]   = wt[t];
                k++;
            }
        }
        if (k) {
            int base = atomicAdd(&cnt, k);
            for (int s = 0; s < k; s++) { goff[base + s] = myoff[s]; gw[base + s] = myw[s]; }
        }
    }
    __syncthreads();
    int C = cnt;
    h16* slab = agg16 + (size_t)cam * 32768 + n * 256;
    if (C == 0) { slab[tid] = (h16)0.f; return; }

    int g8  = (tid & 31) * 8;
    int row = tid >> 5;
    const bf16* fb = ft + (size_t)cam * HW * FD + g8;
    float acc[8] = {0.f, 0.f, 0.f, 0.f, 0.f, 0.f, 0.f, 0.f};
    for (int e = row; e < C; e += 8) {
        float w = gw[e];
        uint4 rv = *(const uint4*)(fb + goff[e]);
        acc[0] += w * bflo(rv.x); acc[1] += w * bfhi(rv.x);
        acc[2] += w * bflo(rv.y); acc[3] += w * bfhi(rv.y);
        acc[4] += w * bflo(rv.z); acc[5] += w * bfhi(rv.z);
        acc[6] += w * bflo(rv.w); acc[7] += w * bfhi(rv.w);
    }
#pragma unroll
    for (int j = 0; j < 8; j++) part[row][g8 + j] = acc[j];
    __syncthreads();
    float s = 0.f;
#pragma unroll
    for (int r = 0; r < 8; r++) s += part[r][tid];
    slab[tid] = (h16)(s * (1.0f / 576.0f));
}

// ---------------------------------------------------------------------------
extern "C" void kernel_launch(void* const* d_in, const int* in_sizes, int n_in,
                              void* d_out, int out_size, void* d_ws, size_t ws_size,
                              hipStream_t stream)
{
    const float* features  = (const float*)d_in[0];
    const float* proj      = (const float*)d_in[1];
    const float* queries0  = (const float*)d_in[3];
    const float* pmin      = (const float*)d_in[4];
    const float* pmax      = (const float*)d_in[5];
    const float* motion_w1 = (const float*)d_in[6];
    const float* motion_b1 = (const float*)d_in[7];
    const float* motion_w2 = (const float*)d_in[8];
    const float* motion_b2 = (const float*)d_in[9];
    const float* type_w1   = (const float*)d_in[10];
    const float* type_b1   = (const float*)d_in[11];
    const float* type_w2   = (const float*)d_in[12];
    const float* type_b2   = (const float*)d_in[13];
    const float* attr_w1   = (const float*)d_in[14];
    const float* attr_b1   = (const float*)d_in[15];
    const float* attr_w2   = (const float*)d_in[16];
    const float* attr_b2   = (const float*)d_in[17];
    const float* fmlp_w1   = (const float*)d_in[18];
    const float* fmlp_b1   = (const float*)d_in[19];
    const float* fmlp_w2   = (const float*)d_in[20];
    const float* fmlp_b2   = (const float*)d_in[21];
    const float* sa_in_w   = (const float*)d_in[22];
    const float* sa_in_b   = (const float*)d_in[23];
    const float* sa_out_w  = (const float*)d_in[24];
    const float* sa_out_b  = (const float*)d_in[25];
    const float* fa_in_w   = (const float*)d_in[26];
    const float* fa_in_b   = (const float*)d_in[27];
    const float* fa_out_w  = (const float*)d_in[28];
    const float* fa_out_b  = (const float*)d_in[29];
    const float* ffn_w1    = (const float*)d_in[30];
    const float* ffn_b1    = (const float*)d_in[31];
    const float* ffn_w2    = (const float*)d_in[32];
    const float* ffn_b2    = (const float*)d_in[33];
    const float* ln1_g     = (const float*)d_in[34];
    const float* ln1_b     = (const float*)d_in[35];
    const float* ln2_g     = (const float*)d_in[36];
    const float* ln2_b     = (const float*)d_in[37];
    const float* ln3_g     = (const float*)d_in[38];
    const float* ln3_b     = (const float*)d_in[39];
    float* out = (float*)d_out;

    // ---- workspace ----
    char* p = (char*)d_ws;
    bf16* feat_t = (bf16*)p;   p += (size_t)NC * HW * FD * 2;        // 17.7 MB
    h16* swz     = (h16*)p;    p += (size_t)51456 * 512 * 2;         // 52.7 MB
    h16* q016    = (h16*)p;    p += 65536 * 2;
    h16* hid16   = (h16*)p;    p += 196608 * 2;
    h16* agg16   = (h16*)p;    p += 196608 * 2;
    h16* fmlph16 = (h16*)p;    p += 65536 * 2;
    h16* feath16 = (h16*)p;    p += 65536 * 2;
    h16* attnb16 = (h16*)p;    p += 65536 * 2;
    h16* ffnh16  = (h16*)p;    p += 262144 * 2;
    h16* qn16    = (h16*)p;    p += 65536 * 2;
    float* qkv   = (float*)p;  p += 196608 * 4;
    float* lnx   = (float*)p;  p += 65536 * 4;
    float* x1    = (float*)p;  p += 65536 * 4;
    float* x2    = (float*)p;  p += 65536 * 4;
    float* qn32  = (float*)p;  p += 65536 * 4;

    // ---- one-time prep (swizzle + transpose + cvt fused) ----
    SwzDesc sd;
    const float* srcs[11] = {motion_w1, type_w1, attr_w1, fmlp_w1, fmlp_w2,
                             sa_in_w, sa_out_w, fa_in_w, fa_out_w, ffn_w1, ffn_w2};
    int Ks[11]    = {512, 512, 512, 256, 512, 512, 512, 512, 512, 512, 2048};
    int tiles[11] = {512, 512, 512, 256, 512, 9216, 3072, 9216, 3072, 12288, 12288};
    unsigned int cumT = 0, cumC = 0;
    for (int i = 0; i < 11; i++) {
        sd.src[i] = srcs[i]; sd.K[i] = Ks[i];
        sd.tileStart[i] = cumT; sd.chunkStart[i] = cumC;
        cumT += tiles[i]; cumC += tiles[i] >> 3;
    }
    sd.chunkStart[11] = cumC;   // 6432

    prep_k<<<15328, 256, 0, stream>>>(sd, swz, features, feat_t, queries0, q016);

    // swizzled weight bases (halfs)
    const h16* sw_heads = swz;                      // motion|type|attr, N=1536,K=512
    const h16* sw_fmlp1 = swz + 786432;             // K=256
    const h16* sw_fmlp2 = swz + 917504;
    const h16* sw_sain  = swz + 1179648;            // + i*786432
    const h16* sw_saout = swz + 5898240;            // + i*262144
    const h16* sw_fain  = swz + 7471104;            // + i*786432
    const h16* sw_faout = swz + 12189696;           // + i*262144
    const h16* sw_ffn1  = swz + 13762560;           // + i*1048576
    const h16* sw_ffn2  = swz + 20054016;           // + i*1048576

    const h16*   q16 = q016;
    const float* q32 = queries0;

    for (int i = 0; i < 6; i++) {
        // D1: prediction heads hidden GEMM
        gemm_sk4<2, 1, false, false><<<dim3(48, 8), 256, 0, stream>>>(
            q16, 512, 0, nullptr, nullptr, nullptr, nullptr, nullptr, 0,
            sw_heads, motion_b1, type_b1, attr_b1, nullptr, 0,
            nullptr, hid16, 1536, 512, 1);

        if (i == 5) {
            heads2_k<<<dim3(128, 24), 64, 0, stream>>>(hid16, motion_w2, motion_b2,
                                                       type_w2, type_b2, attr_w2, attr_b2,
                                                       pmin, pmax, out + i * 3072);
            break;
        }

        // D2: heads2 || sa_in projection (LN1 fused)
        d2_k<<<dim3(144, 8), 256, 0, stream>>>(
            q32, ln1_g + i * 512, ln1_b + i * 512, lnx,
            sw_sain + (size_t)i * 786432, sa_in_b + i * 1536, qkv,
            hid16, motion_w2, motion_b2, type_w2, type_b2, attr_w2, attr_b2,
            pmin, pmax, out + i * 3072);

        // D3: feature gather
        gather_k<<<dim3(128, 6), 256, 0, stream>>>(feat_t, proj, out + i * 3072, agg16);

        // D4: fmlp1 || self-attn core
        d4_k<<<dim3(36, 8), 256, 0, stream>>>(
            agg16, sw_fmlp1, fmlp_b1, fmlph16, qkv, attnb16);

        // D5: fmlp2 || sa_out (+residual lnx)
        d5_k<<<dim3(64, 8), 256, 0, stream>>>(
            fmlph16, sw_fmlp2, fmlp_b2, feath16,
            attnb16, sw_saout + (size_t)i * 262144, sa_out_b + i * 512, lnx, x1);

        // D6: cross-attention projection (LN2 fused; kv side reads feath16)
        gemm_sk4<2, 1, true, true><<<dim3(48, 8), 256, 0, stream>>>(
            nullptr, 0, 0, x1, ln2_g + i * 512, ln2_b + i * 512, lnx, feath16, 16,
            sw_fain + (size_t)i * 786432, fa_in_b + i * 1536, nullptr, nullptr,
            nullptr, 0, qkv, nullptr, 1536, 512, 0);

        // D7: cross-attn core
        attn_k<<<32, 256, 0, stream>>>(qkv, attnb16);

        // D8: fa_out (+residual lnx)
        gemm_sk4<1, 1, false, false><<<dim3(32, 8), 256, 0, stream>>>(
            attnb16, 512, 0, nullptr, nullptr, nullptr, nullptr, nullptr, 0,
            sw_faout + (size_t)i * 262144, fa_out_b + i * 512, nullptr, nullptr,
            lnx, 512, x2, nullptr, 512, 512, 0);

        // D9: FFN1 (LN3 fused)
        gemm_sk4<2, 1, false, true><<<dim3(64, 8), 256, 0, stream>>>(
            nullptr, 0, 0, x2, ln3_g + i * 512, ln3_b + i * 512, lnx, nullptr, 0,
            sw_ffn1 + (size_t)i * 1048576, ffn_b1 + i * 2048, nullptr, nullptr,
            nullptr, 0, nullptr, ffnh16, 2048, 512, 1);

        // D10: FFN2 (+residual lnx)
        gemm_sk4<1, 1, false, false><<<dim3(32, 8), 256, 0, stream>>>(
            ffnh16, 2048, 0, nullptr, nullptr, nullptr, nullptr, nullptr, 0,
            sw_ffn2 + (size_t)i * 1048576, ffn_b2 + i * 512, nullptr, nullptr,
            lnx, 512, qn32, qn16, 512, 2048, 0);

        q16 = qn16;
        q32 = qn32;
    }
}

// Round 5
// 809.610 us; speedup vs baseline: 1.1563x; 1.0068x over previous
//
#include <hip/hip_runtime.h>
#include <hip/hip_bf16.h>

typedef __hip_bfloat16 bf16;
typedef _Float16 h16;
typedef __attribute__((ext_vector_type(8))) _Float16 half8;
typedef __attribute__((ext_vector_type(4))) _Float16 half4;
typedef __attribute__((ext_vector_type(4))) float f32x4;

#define NQ 128
#define HD 512
#define FD 256
#define NC 6
#define IMH 48
#define IMW 120
#define HW 5760   // 48*120

__device__ __forceinline__ half8 pack8(float4 x, float4 y) {
    half8 h;
    h[0] = (h16)x.x; h[1] = (h16)x.y; h[2] = (h16)x.z; h[3] = (h16)x.w;
    h[4] = (h16)y.x; h[5] = (h16)y.y; h[6] = (h16)y.z; h[7] = (h16)y.w;
    return h;
}

// ---------------------------------------------------------------------------
// Weight swizzle descriptor: 11 fp32 row-major matrices -> fp16 MFMA B tiles.
// Global tile g holds: lane l -> W[n64*64 + ct*16 + (l&15)][ks*32 + (l>>4)*8 + j]
// where local = g - tileStart[w] = (n64*(K/32) + ks)*4 + ct.
// Tile stored as 64 lanes x 16B contiguous (1KB). tileStart[11] = total.
// ---------------------------------------------------------------------------
struct SwzDesc {
    const float* src[11];
    unsigned int tileStart[12];    // 12th = sentinel (total tiles)
    int K[11];
};

// ---------------------------------------------------------------------------
// prep2: grid-stride fused prep, 2160 blocks x 256.
//  blocks [0,1536): direct global->reg->global swizzle (1 tile per wave-iter,
//                   no LDS, no barriers, 2 x float4 loads + 1 x 16B store/lane)
//  blocks [1536,2152): 64x64 feature transpose f32 (NC,FD,HW)->(NC,HW,FD) bf16
//                   256B-segment loads, 16B-vector stores
//  blocks [2152,2160): queries0 fp32 -> fp16 (float4 -> half4)
// ---------------------------------------------------------------------------
__global__ __launch_bounds__(256) void prep2_k(SwzDesc d, h16* __restrict__ swz,
                                               const float* __restrict__ feat,
                                               bf16* __restrict__ feat_t,
                                               const float* __restrict__ q0,
                                               h16* __restrict__ q016)
{
    __shared__ float tile[64 * 65];   // transpose staging only
    int bid = blockIdx.x, t = threadIdx.x;

    if (bid < 1536) {
        int wid = bid * 4 + (t >> 6);
        int l = t & 63;
        int lr = l & 15, q8 = (l >> 4) * 8;
        int total = (int)d.tileStart[11];
#pragma unroll 2
        for (int g = wid; g < total; g += 6144) {
            int w = 0;
            while (w < 10 && g >= (int)d.tileStart[w + 1]) w++;
            int local = g - (int)d.tileStart[w];
            int K = d.K[w];
            int K32 = K >> 5;
            int n64 = local / (K32 * 4);
            int rem = local - n64 * (K32 * 4);
            int ks = rem >> 2, ct = rem & 3;
            int row = n64 * 64 + ct * 16 + lr;
            int col = ks * 32 + q8;
            const float* sp = d.src[w] + (size_t)row * K + col;
            float4 u = *(const float4*)sp;
            float4 v = *(const float4*)(sp + 4);
            *(half8*)(swz + (size_t)g * 512 + l * 8) = pack8(u, v);
        }
    } else if (bid < 2152) {
        // transpose: 2160 tiles of 64(hw) x 64(fd), grid-stride over 616 blocks
        for (int g = bid - 1536; g < 2160; g += 616) {
            int cam = g / 360;
            int r = g - cam * 360;
            int fd_t = r / 90, hw_t = r - fd_t * 90;
            int hw0 = hw_t * 64, fd0 = fd_t * 64;
            const float* fb = feat + (size_t)cam * FD * HW;
            // load: 4 passes, 16 fd-rows each; 16 lanes x float4 = 256B per row
            int fr_b = t >> 4, c4 = (t & 15) * 4;
#pragma unroll
            for (int p = 0; p < 4; p++) {
                int fr = p * 16 + fr_b;
                float4 u = *(const float4*)&fb[(size_t)(fd0 + fr) * HW + hw0 + c4];
                tile[fr * 65 + c4 + 0] = u.x;
                tile[fr * 65 + c4 + 1] = u.y;
                tile[fr * 65 + c4 + 2] = u.z;
                tile[fr * 65 + c4 + 3] = u.w;
            }
            __syncthreads();
            // store: 2 passes, 32 hw-rows each; 8 lanes x 8 bf16 (16B) = 128B/row
            bf16* fo = feat_t + (size_t)cam * HW * FD;
            int hr_b = t >> 3, j = t & 7;
#pragma unroll
            for (int s = 0; s < 2; s++) {
                int hr = s * 32 + hr_b;
                union { ushort us[8]; uint4 u4; } pk;
#pragma unroll
                for (int e = 0; e < 8; e++) {
                    bf16 b = __float2bfloat16(tile[(j * 8 + e) * 65 + hr]);
                    pk.us[e] = *(const ushort*)&b;
                }
                *(uint4*)&fo[(size_t)(hw0 + hr) * FD + fd0 + j * 8] = pk.u4;
            }
            __syncthreads();
        }
    } else {
        // cvt: 65536 floats = 16384 float4 tasks over 8 blocks x 256
        for (int i = (bid - 2152) * 256 + t; i < 16384; i += 2048) {
            float4 u = *(const float4*)(q0 + (size_t)i * 4);
            half4 h; h[0] = (h16)u.x; h[1] = (h16)u.y; h[2] = (h16)u.z; h[3] = (h16)u.w;
            *(half4*)(q016 + (size_t)i * 4) = h;
        }
    }
}

// ---------------------------------------------------------------------------
// Split-K-in-block MFMA GEMM body on swizzled fp16 weights (unchanged).
// ---------------------------------------------------------------------------
template<int CTN, int NSUM, bool A2SW, bool LNA>
__device__ __forceinline__ void gemm_body(int bx, int by, int tid,
    float* redu, float* sst, float* sst2,
    const h16* __restrict__ A16, int lda, int sumStride,
    const float* __restrict__ A32,
    const float* __restrict__ lng, const float* __restrict__ lnb,
    float* __restrict__ lnout,
    const h16* __restrict__ A2_16, int a2Start,
    const h16* __restrict__ Wswz,
    const float* __restrict__ B0, const float* __restrict__ B1, const float* __restrict__ B2s,
    const float* __restrict__ R, int ldr,
    float* __restrict__ C32, h16* __restrict__ C16, int ldc,
    int K, int act)
{
    int w = tid >> 6, l = tid & 63;
    int lr = l & 15, q4 = l >> 4;
    int m0 = by * 16;
    int n0 = bx * 16 * CTN;
    int row = m0 + lr;
    int K32 = K >> 5;
    int KQ = K32 >> 2;
    int ks0 = w * KQ;

    bool useA2 = A2SW && (bx >= a2Start);

    const float* arow32 = nullptr;
    float mean = 0.f, rstd = 1.f;
    if (LNA && !useA2) {
        arow32 = A32 + (size_t)row * K + q4 * 8;
        float s = 0.f, s2 = 0.f;
        for (int ks = ks0; ks < ks0 + KQ; ks++) {
            float4 u = *(const float4*)(arow32 + ks * 32);
            float4 v = *(const float4*)(arow32 + ks * 32 + 4);
            s  += u.x + u.y + u.z + u.w + v.x + v.y + v.z + v.w;
            s2 += u.x*u.x + u.y*u.y + u.z*u.z + u.w*u.w
                + v.x*v.x + v.y*v.y + v.z*v.z + v.w*v.w;
        }
        s  += __shfl_xor(s, 16);  s  += __shfl_xor(s, 32);
        s2 += __shfl_xor(s2, 16); s2 += __shfl_xor(s2, 32);
        if (q4 == 0) { sst[w * 16 + lr] = s; sst2[w * 16 + lr] = s2; }
        __syncthreads();
        float st = sst[lr] + sst[16 + lr] + sst[32 + lr] + sst[48 + lr];
        float st2 = sst2[lr] + sst2[16 + lr] + sst2[32 + lr] + sst2[48 + lr];
        mean = st * (1.0f / (float)K);
        float var = st2 * (1.0f / (float)K) - mean * mean;
        rstd = rsqrtf(var + 1e-5f);
    }

    const h16* arow16 = nullptr;
    if (useA2)       arow16 = A2_16 + (size_t)row * 512 + q4 * 8;
    else if (!LNA)   arow16 = A16 + (size_t)row * lda + q4 * 8;

    const h16* wbase[CTN];
#pragma unroll
    for (int ct = 0; ct < CTN; ct++) {
        int tct = (n0 >> 4) + ct;
        wbase[ct] = Wswz + (((size_t)(tct >> 2) * K32 * 4 + (tct & 3)) * 64 + l) * 8;
    }

    f32x4 acc[CTN];
#pragma unroll
    for (int ct = 0; ct < CTN; ct++) acc[ct] = (f32x4){0.f, 0.f, 0.f, 0.f};

    bool wrln = LNA && !useA2 && (bx == 0) && lnout;

#pragma unroll 4
    for (int ks = ks0; ks < ks0 + KQ; ks++) {
        half8 a;
        if (LNA && !useA2) {
            float4 u = *(const float4*)(arow32 + ks * 32);
            float4 v = *(const float4*)(arow32 + ks * 32 + 4);
            float4 g0 = *(const float4*)(lng + ks * 32 + q4 * 8);
            float4 g1 = *(const float4*)(lng + ks * 32 + q4 * 8 + 4);
            float4 b0 = *(const float4*)(lnb + ks * 32 + q4 * 8);
            float4 b1 = *(const float4*)(lnb + ks * 32 + q4 * 8 + 4);
            float4 o0, o1;
            o0.x = (u.x - mean) * rstd * g0.x + b0.x;
            o0.y = (u.y - mean) * rstd * g0.y + b0.y;
            o0.z = (u.z - mean) * rstd * g0.z + b0.z;
            o0.w = (u.w - mean) * rstd * g0.w + b0.w;
            o1.x = (v.x - mean) * rstd * g1.x + b1.x;
            o1.y = (v.y - mean) * rstd * g1.y + b1.y;
            o1.z = (v.z - mean) * rstd * g1.z + b1.z;
            o1.w = (v.w - mean) * rstd * g1.w + b1.w;
            if (wrln) {
                *(float4*)(lnout + (size_t)row * K + ks * 32 + q4 * 8)     = o0;
                *(float4*)(lnout + (size_t)row * K + ks * 32 + q4 * 8 + 4) = o1;
            }
            a = pack8(o0, o1);
        } else if (NSUM == 1) {
            a = *(const half8*)(arow16 + (size_t)ks * 32);
        } else {
            float s[8] = {0.f, 0.f, 0.f, 0.f, 0.f, 0.f, 0.f, 0.f};
#pragma unroll
            for (int j = 0; j < NSUM; j++) {
                half8 tt = *(const half8*)(arow16 + (size_t)j * sumStride + ks * 32);
#pragma unroll
                for (int e = 0; e < 8; e++) s[e] += (float)tt[e];
            }
#pragma unroll
            for (int e = 0; e < 8; e++) a[e] = (h16)s[e];
        }
#pragma unroll
        for (int ct = 0; ct < CTN; ct++) {
            half8 bfr = *(const half8*)(wbase[ct] + (size_t)ks * 2048);
            acc[ct] = __builtin_amdgcn_mfma_f32_16x16x32_f16(a, bfr, acc[ct], 0, 0, 0);
        }
    }

#pragma unroll
    for (int ct = 0; ct < CTN; ct++)
        *(f32x4*)&redu[(size_t)(w * CTN + ct) * 256 + l * 4] = acc[ct];
    __syncthreads();

    if (w < CTN) {
        int ct = w;
        f32x4 sum = *(const f32x4*)&redu[(size_t)ct * 256 + l * 4];
#pragma unroll
        for (int w2 = 1; w2 < 4; w2++) {
            f32x4 tt = *(const f32x4*)&redu[(size_t)(w2 * CTN + ct) * 256 + l * 4];
            sum[0] += tt[0]; sum[1] += tt[1]; sum[2] += tt[2]; sum[3] += tt[3];
        }
        int n = n0 + ct * 16 + lr;
        float bv;
        if (B1) { int sec = n >> 9, ni = n & 511;
                  bv = (sec == 0) ? B0[ni] : (sec == 1 ? B1[ni] : B2s[ni]); }
        else bv = B0[n];
#pragma unroll
        for (int r = 0; r < 4; r++) {
            int m = m0 + q4 * 4 + r;
            float v = sum[r] + bv;
            if (act) v = fmaxf(v, 0.f);
            if (R) v += R[(size_t)m * ldr + n];
            if (C32) C32[(size_t)m * ldc + n] = v;
            if (C16) C16[(size_t)m * ldc + n] = (h16)v;
        }
    }
}

// ---- head output body: one wave per (q, n) ----
__device__ __forceinline__ void heads2_body(int q, int n, int lane,
    const h16* __restrict__ hid16,
    const float* __restrict__ w2m, const float* __restrict__ b2m,
    const float* __restrict__ w2t, const float* __restrict__ b2t,
    const float* __restrict__ w2a, const float* __restrict__ b2a,
    const float* __restrict__ pmin, const float* __restrict__ pmax,
    float* __restrict__ out)
{
    const float* wr; float bv; int mode, sect;
    if (n < 11)      { sect = 0; wr = w2m + n * 512;        bv = b2m[n];      mode = 0; }
    else if (n < 21) { sect = 1; wr = w2t + (n - 11) * 512; bv = b2t[n - 11]; mode = 1; }
    else             { sect = 2; wr = w2a + (n - 21) * 512; bv = b2a[n - 21]; mode = 2; }
    half8 hv = *(const half8*)(hid16 + q * 1536 + sect * 512 + lane * 8);
    const float4* w4 = (const float4*)(wr + lane * 8);
    float4 c0 = w4[0], c1 = w4[1];
    float acc = (float)hv[0] * c0.x + (float)hv[1] * c0.y
              + (float)hv[2] * c0.z + (float)hv[3] * c0.w
              + (float)hv[4] * c1.x + (float)hv[5] * c1.y
              + (float)hv[6] * c1.z + (float)hv[7] * c1.w;
    for (int off = 32; off; off >>= 1) acc += __shfl_xor(acc, off);
    if (lane == 0) {
        float v = acc + bv;
        if (mode == 0)      v = (1.0f / (1.0f + __expf(-v))) * (pmax[n] - pmin[n]) + pmin[n];
        else if (mode == 2) v = 1.0f / (1.0f + __expf(-v));
        out[q * 24 + n] = v;
    }
}

// ---- MHA core body on packed qkv (128 x 1536 = [Q|K|V] fp32) ----
__device__ __forceinline__ void attn_body(int bid, int tid,
                                          float* KVl, float* Ql, float* Pl,
                                          const float* __restrict__ qkv,
                                          h16* __restrict__ out16)
{
    int h = bid >> 2, chunk = bid & 3;

    for (int l = tid; l < 2048; l += 256) {
        int row = l >> 4, c4 = (l & 15) * 4;
        float4 v = *(const float4*)&qkv[row * 1536 + 512 + h * 64 + c4];
        *(float4*)&KVl[row * 68 + c4] = v;
    }
    for (int l = tid; l < 512; l += 256) {
        int row = l >> 4, c4 = (l & 15) * 4;
        float4 v = *(const float4*)&qkv[(chunk * 32 + row) * 1536 + h * 64 + c4];
        *(float4*)&Ql[row * 68 + c4] = v;
    }
    __syncthreads();

    int w = tid >> 6, j = tid & 63;
    for (int r8 = 0; r8 < 8; r8++) {
        int lr = w * 8 + r8;
        float s0 = 0.f, s1 = 0.f;
#pragma unroll
        for (int k4 = 0; k4 < 64; k4 += 4) {
            float4 qv  = *(const float4*)&Ql[lr * 68 + k4];
            float4 k0v = *(const float4*)&KVl[j * 68 + k4];
            float4 k1v = *(const float4*)&KVl[(j + 64) * 68 + k4];
            s0 += qv.x * k0v.x + qv.y * k0v.y + qv.z * k0v.z + qv.w * k0v.w;
            s1 += qv.x * k1v.x + qv.y * k1v.y + qv.z * k1v.z + qv.w * k1v.w;
        }
        s0 *= 0.125f; s1 *= 0.125f;
        float m = fmaxf(s0, s1);
        for (int off = 32; off; off >>= 1) m = fmaxf(m, __shfl_xor(m, off));
        float e0 = __expf(s0 - m), e1 = __expf(s1 - m);
        float sm = e0 + e1;
        for (int off = 32; off; off >>= 1) sm += __shfl_xor(sm, off);
        float inv = 1.0f / sm;
        Pl[lr * 128 + j]      = e0 * inv;
        Pl[lr * 128 + j + 64] = e1 * inv;
    }
    __syncthreads();

    for (int l = tid; l < 2048; l += 256) {
        int row = l >> 4, c4 = (l & 15) * 4;
        float4 v = *(const float4*)&qkv[row * 1536 + 1024 + h * 64 + c4];
        KVl[(c4 + 0) * 132 + row] = v.x;
        KVl[(c4 + 1) * 132 + row] = v.y;
        KVl[(c4 + 2) * 132 + row] = v.z;
        KVl[(c4 + 3) * 132 + row] = v.w;
    }
    __syncthreads();

    int d = tid & 63, w2 = tid >> 6;
    for (int r8 = 0; r8 < 8; r8++) {
        int lr = w2 * 8 + r8;
        float o = 0.f;
#pragma unroll
        for (int j4 = 0; j4 < 128; j4 += 4) {
            float4 pv = *(const float4*)&Pl[lr * 128 + j4];
            float4 vv = *(const float4*)&KVl[d * 132 + j4];
            o += pv.x * vv.x + pv.y * vv.y + pv.z * vv.z + pv.w * vv.w;
        }
        out16[(chunk * 32 + lr) * 512 + h * 64 + d] = (h16)o;
    }
}

// ---------------------------------------------------------------------------
// Kernels
// ---------------------------------------------------------------------------

template<int CTN, int NSUM, bool A2SW, bool LNA>
__global__ __launch_bounds__(256) void gemm_sk4(
    const h16* __restrict__ A16, int lda, int sumStride,
    const float* __restrict__ A32,
    const float* __restrict__ lng, const float* __restrict__ lnb,
    float* __restrict__ lnout,
    const h16* __restrict__ A2_16, int a2Start,
    const h16* __restrict__ Wswz,
    const float* __restrict__ B0, const float* __restrict__ B1, const float* __restrict__ B2s,
    const float* __restrict__ R, int ldr,
    float* __restrict__ C32, h16* __restrict__ C16, int ldc,
    int K, int act)
{
    __shared__ float redu[CTN * 4 * 256];
    __shared__ float sst[64], sst2[64];
    gemm_body<CTN, NSUM, A2SW, LNA>(blockIdx.x, blockIdx.y, threadIdx.x,
        redu, sst, sst2, A16, lda, sumStride, A32, lng, lnb, lnout, A2_16, a2Start,
        Wswz, B0, B1, B2s, R, ldr, C32, C16, ldc, K, act);
}

__global__ __launch_bounds__(64) void heads2_k(const h16* __restrict__ hid16,
                                               const float* __restrict__ w2m, const float* __restrict__ b2m,
                                               const float* __restrict__ w2t, const float* __restrict__ b2t,
                                               const float* __restrict__ w2a, const float* __restrict__ b2a,
                                               const float* __restrict__ pmin, const float* __restrict__ pmax,
                                               float* __restrict__ out)
{
    heads2_body(blockIdx.x, blockIdx.y, threadIdx.x,
                hid16, w2m, b2m, w2t, b2t, w2a, b2a, pmin, pmax, out);
}

__global__ __launch_bounds__(256) void attn_k(const float* __restrict__ qkv,
                                              h16* __restrict__ out16)
{
    __shared__ float KVl[128 * 68];
    __shared__ float Ql[32 * 68];
    __shared__ float Pl[32 * 128];
    attn_body(blockIdx.x, threadIdx.x, KVl, Ql, Pl, qkv, out16);
}

// D2: heads2 (x>=48, 4 waves = 4 (q,n) pairs per block) || sa_in GEMM (x<48)
__global__ __launch_bounds__(256) void d2_k(
    const float* __restrict__ q32, const float* __restrict__ lng,
    const float* __restrict__ lnb, float* __restrict__ lnx,
    const h16* __restrict__ Wsain, const float* __restrict__ Bsain,
    float* __restrict__ qkv,
    const h16* __restrict__ hid16,
    const float* __restrict__ w2m, const float* __restrict__ b2m,
    const float* __restrict__ w2t, const float* __restrict__ b2t,
    const float* __restrict__ w2a, const float* __restrict__ b2a,
    const float* __restrict__ pmin, const float* __restrict__ pmax,
    float* __restrict__ out)
{
    __shared__ float redu[2 * 4 * 256];
    __shared__ float sst[64], sst2[64];
    int x = blockIdx.x, by = blockIdx.y, tid = threadIdx.x;
    if (x < 48) {
        gemm_body<2, 1, false, true>(x, by, tid, redu, sst, sst2,
            nullptr, 0, 0, q32, lng, lnb, lnx, nullptr, 0,
            Wsain, Bsain, nullptr, nullptr, nullptr, 0,
            qkv, nullptr, 1536, 512, 0);
    } else {
        int p = (((x - 48) * 8 + by) << 2) + (tid >> 6);   // 0..3071
        heads2_body(p / 24, p % 24, tid & 63,
                    hid16, w2m, b2m, w2t, b2t, w2a, b2a, pmin, pmax, out);
    }
}

// D4: fmlp1 GEMM (x<32) || self-attn core (x>=32, slot=(x-32)*8+by)
__global__ __launch_bounds__(256) void d4_k(
    const h16* __restrict__ agg16, const h16* __restrict__ Wf1,
    const float* __restrict__ Bf1, h16* __restrict__ fmlph16,
    const float* __restrict__ qkv, h16* __restrict__ attnb16)
{
    __shared__ float smem[14976];   // attn: KVl 8704 | Ql 2176 | Pl 4096
    int x = blockIdx.x, by = blockIdx.y, tid = threadIdx.x;
    if (x < 32) {
        gemm_body<1, 6, false, false>(x, by, tid, smem, smem + 1024, smem + 1088,
            agg16, 256, 32768, nullptr, nullptr, nullptr, nullptr, nullptr, 0,
            Wf1, Bf1, nullptr, nullptr, nullptr, 0,
            nullptr, fmlph16, 512, 256, 1);
    } else {
        int slot = (x - 32) * 8 + by;   // 0..31
        attn_body(slot, tid, smem, smem + 8704, smem + 10880, qkv, attnb16);
    }
}

// D5: fmlp2 GEMM (x<32) || sa_out GEMM (x>=32)
__global__ __launch_bounds__(256) void d5_k(
    const h16* __restrict__ fmlph16, const h16* __restrict__ Wf2,
    const float* __restrict__ Bf2, h16* __restrict__ feath16,
    const h16* __restrict__ attnb16, const h16* __restrict__ Wso,
    const float* __restrict__ Bso, const float* __restrict__ lnx,
    float* __restrict__ x1)
{
    __shared__ float redu[1024];
    __shared__ float sst[64], sst2[64];
    int x = blockIdx.x, by = blockIdx.y, tid = threadIdx.x;
    if (x < 32) {
        gemm_body<1, 1, false, false>(x, by, tid, redu, sst, sst2,
            fmlph16, 512, 0, nullptr, nullptr, nullptr, nullptr, nullptr, 0,
            Wf2, Bf2, nullptr, nullptr, nullptr, 0,
            nullptr, feath16, 512, 512, 0);
    } else {
        gemm_body<1, 1, false, false>(x - 32, by, tid, redu, sst, sst2,
            attnb16, 512, 0, nullptr, nullptr, nullptr, nullptr, nullptr, 0,
            Wso, Bso, nullptr, nullptr, lnx, 512,
            x1, nullptr, 512, 512, 0);
    }
}

// ---------------------------------------------------------------------------
// Gather: grid (128 queries, 6 cams). Compacted taps; fp16 slab out.
// ---------------------------------------------------------------------------
__device__ __forceinline__ float bflo(unsigned u) {
    union { unsigned i; float f; } c; c.i = u << 16; return c.f;
}
__device__ __forceinline__ float bfhi(unsigned u) {
    union { unsigned i; float f; } c; c.i = u & 0xffff0000u; return c.f;
}

__global__ __launch_bounds__(256) void gather_k(const bf16* __restrict__ ft,
                                                const float* __restrict__ proj,
                                                const float* __restrict__ preds,
                                                h16* __restrict__ agg16)
{
    __shared__ float mo[11];
    __shared__ int   goff[384];
    __shared__ float gw[384];
    __shared__ int   cnt;
    __shared__ float part[8][256];
    int n = blockIdx.x, cam = blockIdx.y, tid = threadIdx.x;
    if (tid == 0) cnt = 0;
    if (tid < 11) mo[tid] = preds[n * 24 + tid];
    __syncthreads();

    if (tid < 96) {
        int p = tid;
        float dd0 = mo[8], dd1 = mo[9], dd2 = mo[10];
        float c0 = mo[0], c1 = mo[1], c2 = mo[2];
        float sy, cy;
        sincosf(mo[7], &sy, &cy);
        int face = p >> 4, axis = face >> 1;
        float sgn = (face & 1) ? 0.5f : -0.5f;
        float offi = -0.4f + (float)((p >> 2) & 3) * (0.8f / 3.0f);
        float offj = -0.4f + (float)(p & 3) * (0.8f / 3.0f);
        float t0, t1, t2;
        if (axis == 0)      { t0 = sgn;  t1 = offi; t2 = offj; }
        else if (axis == 1) { t0 = offi; t1 = sgn;  t2 = offj; }
        else                { t0 = offi; t1 = offj; t2 = sgn;  }
        float px = t0 * dd0, py = t1 * dd1, pz = t2 * dd2;
        float X = px * cy - py * sy + c0;
        float Y = px * sy + py * cy + c1;
        float Z = pz + c2;
        const float* P = proj + cam * 12;
        float cu = P[0] * X + P[1] * Y + P[2] * Z + P[3];
        float cv = P[4] * X + P[5] * Y + P[6] * Z + P[7];
        float cz = P[8] * X + P[9] * Y + P[10] * Z + P[11];
        float zs = (fabsf(cz) > 1e-6f) ? cz : 1e-6f;
        float u = cu / zs, v = cv / zs;
        bool front = cz > 0.0f;
        float u0 = floorf(u), v0 = floorf(v);
        float du = u - u0, dv = v - v0;
        float us[4] = {u0, u0 + 1.0f, u0, u0 + 1.0f};
        float vs[4] = {v0, v0, v0 + 1.0f, v0 + 1.0f};
        float wt[4] = {(1.0f - du) * (1.0f - dv), du * (1.0f - dv),
                       (1.0f - du) * dv, du * dv};
        int   myoff[4]; float myw[4]; int k = 0;
#pragma unroll
        for (int t = 0; t < 4; t++) {
            bool ok = front && (us[t] >= 0.0f) && (us[t] <= 119.0f)
                            && (vs[t] >= 0.0f) && (vs[t] <= 47.0f)
                            && (wt[t] > 0.0f);
            if (ok) {
                myoff[k] = ((int)vs[t] * IMW + (int)us[t]) * FD;
                myw[k]   = wt[t];
                k++;
            }
        }
        if (k) {
            int base = atomicAdd(&cnt, k);
            for (int s = 0; s < k; s++) { goff[base + s] = myoff[s]; gw[base + s] = myw[s]; }
        }
    }
    __syncthreads();
    int C = cnt;
    h16* slab = agg16 + (size_t)cam * 32768 + n * 256;
    if (C == 0) { slab[tid] = (h16)0.f; return; }

    int g8  = (tid & 31) * 8;
    int row = tid >> 5;
    const bf16* fb = ft + (size_t)cam * HW * FD + g8;
    float acc[8] = {0.f, 0.f, 0.f, 0.f, 0.f, 0.f, 0.f, 0.f};
    for (int e = row; e < C; e += 8) {
        float w = gw[e];
        uint4 rv = *(const uint4*)(fb + goff[e]);
        acc[0] += w * bflo(rv.x); acc[1] += w * bfhi(rv.x);
        acc[2] += w * bflo(rv.y); acc[3] += w * bfhi(rv.y);
        acc[4] += w * bflo(rv.z); acc[5] += w * bfhi(rv.z);
        acc[6] += w * bflo(rv.w); acc[7] += w * bfhi(rv.w);
    }
#pragma unroll
    for (int j = 0; j < 8; j++) part[row][g8 + j] = acc[j];
    __syncthreads();
    float s = 0.f;
#pragma unroll
    for (int r = 0; r < 8; r++) s += part[r][tid];
    slab[tid] = (h16)(s * (1.0f / 576.0f));
}

// ---------------------------------------------------------------------------
extern "C" void kernel_launch(void* const* d_in, const int* in_sizes, int n_in,
                              void* d_out, int out_size, void* d_ws, size_t ws_size,
                              hipStream_t stream)
{
    const float* features  = (const float*)d_in[0];
    const float* proj      = (const float*)d_in[1];
    const float* queries0  = (const float*)d_in[3];
    const float* pmin      = (const float*)d_in[4];
    const float* pmax      = (const float*)d_in[5];
    const float* motion_w1 = (const float*)d_in[6];
    const float* motion_b1 = (const float*)d_in[7];
    const float* motion_w2 = (const float*)d_in[8];
    const float* motion_b2 = (const float*)d_in[9];
    const float* type_w1   = (const float*)d_in[10];
    const float* type_b1   = (const float*)d_in[11];
    const float* type_w2   = (const float*)d_in[12];
    const float* type_b2   = (const float*)d_in[13];
    const float* attr_w1   = (const float*)d_in[14];
    const float* attr_b1   = (const float*)d_in[15];
    const float* attr_w2   = (const float*)d_in[16];
    const float* attr_b2   = (const float*)d_in[17];
    const float* fmlp_w1   = (const float*)d_in[18];
    const float* fmlp_b1   = (const float*)d_in[19];
    const float* fmlp_w2   = (const float*)d_in[20];
    const float* fmlp_b2   = (const float*)d_in[21];
    const float* sa_in_w   = (const float*)d_in[22];
    const float* sa_in_b   = (const float*)d_in[23];
    const float* sa_out_w  = (const float*)d_in[24];
    const float* sa_out_b  = (const float*)d_in[25];
    const float* fa_in_w   = (const float*)d_in[26];
    const float* fa_in_b   = (const float*)d_in[27];
    const float* fa_out_w  = (const float*)d_in[28];
    const float* fa_out_b  = (const float*)d_in[29];
    const float* ffn_w1    = (const float*)d_in[30];
    const float* ffn_b1    = (const float*)d_in[31];
    const float* ffn_w2    = (const float*)d_in[32];
    const float* ffn_b2    = (const float*)d_in[33];
    const float* ln1_g     = (const float*)d_in[34];
    const float* ln1_b     = (const float*)d_in[35];
    const float* ln2_g     = (const float*)d_in[36];
    const float* ln2_b     = (const float*)d_in[37];
    const float* ln3_g     = (const float*)d_in[38];
    const float* ln3_b     = (const float*)d_in[39];
    float* out = (float*)d_out;

    // ---- workspace ----
    char* p = (char*)d_ws;
    bf16* feat_t = (bf16*)p;   p += (size_t)NC * HW * FD * 2;        // 17.7 MB
    h16* swz     = (h16*)p;    p += (size_t)51456 * 512 * 2;         // 52.7 MB
    h16* q016    = (h16*)p;    p += 65536 * 2;
    h16* hid16   = (h16*)p;    p += 196608 * 2;
    h16* agg16   = (h16*)p;    p += 196608 * 2;
    h16* fmlph16 = (h16*)p;    p += 65536 * 2;
    h16* feath16 = (h16*)p;    p += 65536 * 2;
    h16* attnb16 = (h16*)p;    p += 65536 * 2;
    h16* ffnh16  = (h16*)p;    p += 262144 * 2;
    h16* qn16    = (h16*)p;    p += 65536 * 2;
    float* qkv   = (float*)p;  p += 196608 * 4;
    float* lnx   = (float*)p;  p += 65536 * 4;
    float* x1    = (float*)p;  p += 65536 * 4;
    float* x2    = (float*)p;  p += 65536 * 4;
    float* qn32  = (float*)p;  p += 65536 * 4;

    // ---- one-time prep (direct swizzle + transpose + cvt, grid-stride) ----
    SwzDesc sd;
    const float* srcs[11] = {motion_w1, type_w1, attr_w1, fmlp_w1, fmlp_w2,
                             sa_in_w, sa_out_w, fa_in_w, fa_out_w, ffn_w1, ffn_w2};
    int Ks[11]    = {512, 512, 512, 256, 512, 512, 512, 512, 512, 512, 2048};
    int tiles[11] = {512, 512, 512, 256, 512, 9216, 3072, 9216, 3072, 12288, 12288};
    unsigned int cumT = 0;
    for (int i = 0; i < 11; i++) {
        sd.src[i] = srcs[i]; sd.K[i] = Ks[i];
        sd.tileStart[i] = cumT;
        cumT += tiles[i];
    }
    sd.tileStart[11] = cumT;   // 51456

    prep2_k<<<2160, 256, 0, stream>>>(sd, swz, features, feat_t, queries0, q016);

    // swizzled weight bases (halfs)
    const h16* sw_heads = swz;                      // motion|type|attr, N=1536,K=512
    const h16* sw_fmlp1 = swz + 786432;             // K=256
    const h16* sw_fmlp2 = swz + 917504;
    const h16* sw_sain  = swz + 1179648;            // + i*786432
    const h16* sw_saout = swz + 5898240;            // + i*262144
    const h16* sw_fain  = swz + 7471104;            // + i*786432
    const h16* sw_faout = swz + 12189696;           // + i*262144
    const h16* sw_ffn1  = swz + 13762560;           // + i*1048576
    const h16* sw_ffn2  = swz + 20054016;           // + i*1048576

    const h16*   q16 = q016;
    const float* q32 = queries0;

    for (int i = 0; i < 6; i++) {
        // D1: prediction heads hidden GEMM
        gemm_sk4<2, 1, false, false><<<dim3(48, 8), 256, 0, stream>>>(
            q16, 512, 0, nullptr, nullptr, nullptr, nullptr, nullptr, 0,
            sw_heads, motion_b1, type_b1, attr_b1, nullptr, 0,
            nullptr, hid16, 1536, 512, 1);

        if (i == 5) {
            heads2_k<<<dim3(128, 24), 64, 0, stream>>>(hid16, motion_w2, motion_b2,
                                                       type_w2, type_b2, attr_w2, attr_b2,
                                                       pmin, pmax, out + i * 3072);
            break;
        }

        // D2: heads2 || sa_in projection (LN1 fused)
        d2_k<<<dim3(144, 8), 256, 0, stream>>>(
            q32, ln1_g + i * 512, ln1_b + i * 512, lnx,
            sw_sain + (size_t)i * 786432, sa_in_b + i * 1536, qkv,
            hid16, motion_w2, motion_b2, type_w2, type_b2, attr_w2, attr_b2,
            pmin, pmax, out + i * 3072);

        // D3: feature gather
        gather_k<<<dim3(128, 6), 256, 0, stream>>>(feat_t, proj, out + i * 3072, agg16);

        // D4: fmlp1 || self-attn core
        d4_k<<<dim3(36, 8), 256, 0, stream>>>(
            agg16, sw_fmlp1, fmlp_b1, fmlph16, qkv, attnb16);

        // D5: fmlp2 || sa_out (+residual lnx)
        d5_k<<<dim3(64, 8), 256, 0, stream>>>(
            fmlph16, sw_fmlp2, fmlp_b2, feath16,
            attnb16, sw_saout + (size_t)i * 262144, sa_out_b + i * 512, lnx, x1);

        // D6: cross-attention projection (LN2 fused; kv side reads feath16)
        gemm_sk4<2, 1, true, true><<<dim3(48, 8), 256, 0, stream>>>(
            nullptr, 0, 0, x1, ln2_g + i * 512, ln2_b + i * 512, lnx, feath16, 16,
            sw_fain + (size_t)i * 786432, fa_in_b + i * 1536, nullptr, nullptr,
            nullptr, 0, qkv, nullptr, 1536, 512, 0);

        // D7: cross-attn core
        attn_k<<<32, 256, 0, stream>>>(qkv, attnb16);

        // D8: fa_out (+residual lnx)
        gemm_sk4<1, 1, false, false><<<dim3(32, 8), 256, 0, stream>>>(
            attnb16, 512, 0, nullptr, nullptr, nullptr, nullptr, nullptr, 0,
            sw_faout + (size_t)i * 262144, fa_out_b + i * 512, nullptr, nullptr,
            lnx, 512, x2, nullptr, 512, 512, 0);

        // D9: FFN1 (LN3 fused)
        gemm_sk4<2, 1, false, true><<<dim3(64, 8), 256, 0, stream>>>(
            nullptr, 0, 0, x2, ln3_g + i * 512, ln3_b + i * 512, lnx, nullptr, 0,
            sw_ffn1 + (size_t)i * 1048576, ffn_b1 + i * 2048, nullptr, nullptr,
            nullptr, 0, nullptr, ffnh16, 2048, 512, 1);

        // D10: FFN2 (+residual lnx)
        gemm_sk4<1, 1, false, false><<<dim3(32, 8), 256, 0, stream>>>(
            ffnh16, 2048, 0, nullptr, nullptr, nullptr, nullptr, nullptr, 0,
            sw_ffn2 + (size_t)i * 1048576, ffn_b2 + i * 512, nullptr, nullptr,
            lnx, 512, qn32, qn16, 512, 2048, 0);

        q16 = qn16;
        q32 = qn32;
    }
}